// Round 5
// baseline (368.399 us; speedup 1.0000x reference)
//
#include <hip/hip_runtime.h>
#include <hip/hip_bf16.h>
#include <stdint.h>

// Problem constants
#define B_    256
#define LS_   1024
#define LW_   1024
#define LV_   1024
#define M_    16
#define D_    5120
#define H_    2048
#define ROWS  4096   // B*M
#define N1    4096   // H (eta) + H (rho) fused
#define KW    2048   // K of the per-row (wr|wi) GEMM

typedef __hip_bfloat16 bf16;
typedef __bf16 bf16x8 __attribute__((ext_vector_type(8)));
typedef float f32x4 __attribute__((ext_vector_type(4)));

#define SB0() __builtin_amdgcn_sched_barrier(0)
#define LGKM(n) asm volatile("s_waitcnt lgkmcnt(" #n ")" ::: "memory")
#define VMC(n)  asm volatile("s_waitcnt vmcnt(" #n ")" ::: "memory")

// ---------------------------------------------------------------------------
// async global->LDS, 16B per lane (HW: wave-uniform LDS base + lane*16).
__device__ __forceinline__ void gld_lds16(const void* g, void* l) {
  auto gp = (const __attribute__((address_space(1))) uint32_t*)(uintptr_t)g;
  auto lp = (__attribute__((address_space(3))) uint32_t*)(uint32_t)(uintptr_t)l;
  __builtin_amdgcn_global_load_lds(gp, lp, 16, 0, 0);
}

// ---------------------------------------------------------------------------
__global__ void sfeat_kernel(const float* __restrict__ phi, bf16* __restrict__ sfeat) {
  int i = blockIdx.x * blockDim.x + threadIdx.x;
  int b = i >> 10, l = i & 1023;
  float p = phi[i];
  float s, c;
  sincosf(p, &s, &c);
  sfeat[b * 2048 + l]        = __float2bfloat16(0.03125f * c);
  sfeat[b * 2048 + 1024 + l] = __float2bfloat16(0.03125f * s);
}

// ---------------------------------------------------------------------------
// Transpose f32 [R,C] -> bf16 [C,R]  (C = row stride of in; full-col blocks)
__global__ void transpose_bf16_kernel(const float* __restrict__ in, bf16* __restrict__ out,
                                      int R, int C) {
  __shared__ float tile[32][33];
  int c0 = blockIdx.x * 32, r0 = blockIdx.y * 32;
  int tx = threadIdx.x, ty = threadIdx.y;   // 32 x 8
#pragma unroll
  for (int i = 0; i < 32; i += 8)
    tile[ty + i][tx] = in[(size_t)(r0 + ty + i) * C + (c0 + tx)];
  __syncthreads();
#pragma unroll
  for (int i = 0; i < 32; i += 8)
    out[(size_t)(c0 + ty + i) * R + (r0 + tx)] = __float2bfloat16(tile[tx][ty + i]);
}

// ---------------------------------------------------------------------------
// Awr [4096, 2048] bf16: row r=b*16+m = [ wr[b,:,m] | wi[b,:,m] ]
// Batched transpose of [64 l x 16 m] tiles via LDS.
__global__ void build_awr_kernel(const float* __restrict__ wr_, const float* __restrict__ wi_,
                                 bf16* __restrict__ Awr) {
  __shared__ float tr[64][17], ti[64][17];
  int b = blockIdx.y, l0 = blockIdx.x * 64;
  int t = threadIdx.x;   // 256
  const float* wrb = wr_ + (size_t)b * (LW_ * M_) + (size_t)l0 * 16;
  const float* wib = wi_ + (size_t)b * (LW_ * M_) + (size_t)l0 * 16;
#pragma unroll
  for (int i = 0; i < 4; ++i) {
    int e = i * 256 + t, l = e >> 4, m = e & 15;
    tr[l][m] = wrb[e];
    ti[l][m] = wib[e];
  }
  __syncthreads();
  int m = t >> 4, t4 = t & 15;    // 16 m x 16 l-quads
  bf16* outR = Awr + (size_t)(b * 16 + m) * KW + l0;
#pragma unroll
  for (int j = 0; j < 4; ++j) outR[t4 * 4 + j]        = __float2bfloat16(tr[t4 * 4 + j][m]);
#pragma unroll
  for (int j = 0; j < 4; ++j) outR[1024 + t4 * 4 + j] = __float2bfloat16(ti[t4 * 4 + j][m]);
}

// ---------------------------------------------------------------------------
// hVT [4096 n, 16 m] f32: hVT[n][m] = sum_l vM[l,m] * W1cat[4096+l, n]
// grid 16 blocks x 256 thr; blocks 0-7 -> W1e cols, 8-15 -> W1r cols.
__global__ void hv_kernel(const float* __restrict__ vM,
                          const float* __restrict__ W1e, const float* __restrict__ W1r,
                          float* __restrict__ hVT) {
  __shared__ float vs[256][16];
  int t = threadIdx.x;
  int n = blockIdx.x * 256 + t;
  const float* Wb = (blockIdx.x < 8) ? W1e : W1r;
  int nc = (blockIdx.x < 8) ? n : n - 2048;
  float acc[16] = {};
  for (int l0 = 0; l0 < 1024; l0 += 256) {
    __syncthreads();
#pragma unroll
    for (int i = 0; i < 16; ++i) {
      int e = i * 256 + t, l = e >> 4, m = e & 15;
      vs[l][m] = vM[(size_t)(l0 + l) * 16 + m];
    }
    __syncthreads();
    for (int ll = 0; ll < 256; ++ll) {
      float w = Wb[(size_t)(4096 + l0 + ll) * 2048 + nc];
#pragma unroll
      for (int m = 0; m < 16; ++m) acc[m] += vs[ll][m] * w;
    }
  }
#pragma unroll
  for (int m = 0; m < 16; ++m) hVT[(size_t)n * 16 + m] = acc[m];
}

// ---------------------------------------------------------------------------
// GEMM_W: 256x256 tile, BK=32, 8 waves (2Mx4N), 4-deep LDS ring, counted
// lgkmcnt pipeline, ONE barrier per K-tile (proven R4 schedule; K=2048).
// Epilogue fuses: h = relu(accW + hS[b,c] + hVT[c, r&15] + bias[c]) -> bf16.
__global__ void __launch_bounds__(512, 2)
gemm1_256_kernel(const bf16* __restrict__ A, const bf16* __restrict__ Bt,
                 const float* __restrict__ bias0, const float* __restrict__ bias1,
                 const float* __restrict__ hS, const float* __restrict__ hVT,
                 bf16* __restrict__ outH) {
  extern __shared__ __align__(16) char smem[];
  constexpr int NT = KW / 32;   // 64 K-tiles

  const int tid  = threadIdx.x;
  const int lane = tid & 63;
  const int wave = tid >> 6;
  const int wr = wave >> 2, wc = wave & 3;   // 2 x 4 wave grid, wave-tile 128x64
  const int fr = lane & 15, fq = lane >> 4;
  const int row0 = blockIdx.y * 256, col0 = blockIdx.x * 256;

  // fragment ds_read lane statics
  const int slotF = (((fr & 1) << 2) | fq) ^ ((fr >> 1) & 7);
  const int aOff = (wr << 13) + ((fr >> 1) << 7) + (slotF << 4);
  const int bOff = 16384 + (wc << 12) + ((fr >> 1) << 7) + (slotF << 4);

  // staging lane statics (two 8KB halves per operand)
  const int lg0 = (tid >> 3), lg1 = 64 + (tid >> 3);
  const int su0 = (tid & 7) ^ (lg0 & 7), su1 = (tid & 7) ^ (lg1 & 7);
  const int rowp0 = lg0 * 2 + (su0 >> 2), rowp1 = lg1 * 2 + (su1 >> 2);
  const int kb0 = (su0 & 3) << 4, kb1 = (su1 & 3) << 4;
  const char* pA0 = (const char*)A  + (size_t)(row0 + rowp0) * (KW * 2) + kb0;
  const char* pA1 = (const char*)A  + (size_t)(row0 + rowp1) * (KW * 2) + kb1;
  const char* pB0 = (const char*)Bt + (size_t)(col0 + rowp0) * (KW * 2) + kb0;
  const char* pB1 = (const char*)Bt + (size_t)(col0 + rowp1) * (KW * 2) + kb1;

  auto stageTile = [&](int T) {   // 4 gld per wave (vmcnt +4)
    char* dst = smem + (size_t)(T & 3) * 32768;
    const size_t ko = (size_t)T * 64;
    gld_lds16(pA0 + ko, dst + 0     + tid * 16);
    gld_lds16(pA1 + ko, dst + 8192  + tid * 16);
    gld_lds16(pB0 + ko, dst + 16384 + tid * 16);
    gld_lds16(pB1 + ko, dst + 24576 + tid * 16);
  };

  f32x4 acc[8][4] = {};
  bf16x8 bA[4], bB[4];

  // prologue: stage tiles 0,1,2; retire 0 (keep 2 flying); pre-read B(t0)
  stageTile(0); stageTile(1); stageTile(2);
  VMC(4);
  __builtin_amdgcn_s_barrier();
  {
    const char* bP = smem + bOff;   // buf0 B
#pragma unroll
    for (int n = 0; n < 4; ++n) bA[n] = *(const bf16x8*)(bP + n * 1024);
  }
  SB0();

  auto doIter = [&](int T, bf16x8 (&bCur)[4], bf16x8 (&bNxt)[4]) {
    const char* aP = smem + (size_t)(T & 3) * 32768 + aOff;
    const char* bP = smem + (size_t)((T + 1) & 3) * 32768 + bOff;
    bf16x8 a[8];
#pragma unroll
    for (int m = 0; m < 4; ++m) a[m] = *(const bf16x8*)(aP + m * 1024);
    SB0();
#pragma unroll
    for (int m = 4; m < 8; ++m) a[m] = *(const bf16x8*)(aP + m * 1024);
    SB0();
#pragma unroll
    for (int n = 0; n < 4; ++n) bNxt[n] = *(const bf16x8*)(bP + n * 1024);
    SB0();
    if (T + 3 < NT) stageTile(T + 3);
    SB0();
    LGKM(8);
    SB0();
    __builtin_amdgcn_s_setprio(1);
#pragma unroll
    for (int m = 0; m < 4; ++m)
#pragma unroll
      for (int n = 0; n < 4; ++n)
        acc[m][n] = __builtin_amdgcn_mfma_f32_16x16x32_bf16(a[m], bCur[n], acc[m][n], 0, 0, 0);
    SB0();
    LGKM(4);
    SB0();
#pragma unroll
    for (int m = 4; m < 8; ++m)
#pragma unroll
      for (int n = 0; n < 4; ++n)
        acc[m][n] = __builtin_amdgcn_mfma_f32_16x16x32_bf16(a[m], bCur[n], acc[m][n], 0, 0, 0);
    __builtin_amdgcn_s_setprio(0);
    SB0();
    LGKM(0);
    if (T + 3 < NT) { VMC(4); }
    else            { VMC(0); }
    __builtin_amdgcn_s_barrier();
  };

  for (int t = 0; t < NT - 2; t += 2) {
    doIter(t,     bA, bB);
    doIter(t + 1, bB, bA);
  }
  doIter(NT - 2, bA, bB);

  {  // final tile NT-1 (uses bB)
    const char* aP = smem + (size_t)((NT - 1) & 3) * 32768 + aOff;
    bf16x8 a[8];
#pragma unroll
    for (int m = 0; m < 4; ++m) a[m] = *(const bf16x8*)(aP + m * 1024);
    SB0();
#pragma unroll
    for (int m = 4; m < 8; ++m) a[m] = *(const bf16x8*)(aP + m * 1024);
    SB0();
    LGKM(4);
    SB0();
    __builtin_amdgcn_s_setprio(1);
#pragma unroll
    for (int m = 0; m < 4; ++m)
#pragma unroll
      for (int n = 0; n < 4; ++n)
        acc[m][n] = __builtin_amdgcn_mfma_f32_16x16x32_bf16(a[m], bB[n], acc[m][n], 0, 0, 0);
    SB0();
    LGKM(0);
    SB0();
#pragma unroll
    for (int m = 4; m < 8; ++m)
#pragma unroll
      for (int n = 0; n < 4; ++n)
        acc[m][n] = __builtin_amdgcn_mfma_f32_16x16x32_bf16(a[m], bB[n], acc[m][n], 0, 0, 0);
    __builtin_amdgcn_s_setprio(0);
  }

  // epilogue: h = relu(accW + hS[b,c] + hVT[c, fq*4+j] + bias[c])
#pragma unroll
  for (int n = 0; n < 4; ++n) {
    const int c = col0 + wc * 64 + n * 16 + fr;
    const float bias = (c < H_) ? bias0[c] : bias1[c - H_];
    const f32x4 hv = *(const f32x4*)&hVT[(size_t)c * 16 + fq * 4];
#pragma unroll
    for (int m = 0; m < 8; ++m) {
      const int rbase = row0 + wr * 128 + m * 16;
      const float hs = hS[(size_t)(rbase >> 4) * N1 + c];
#pragma unroll
      for (int j = 0; j < 4; ++j) {
        const int r = rbase + fq * 4 + j;
        float v = acc[m][n][j] + bias + hs + hv[j];
        outH[(size_t)r * N1 + c] = __float2bfloat16(v > 0.f ? v : 0.f);
      }
    }
  }
}

// ---------------------------------------------------------------------------
// 128x128 m97-style GEMM. EPI 0: eta^T scatter with bias. EPI 1: plain f32
// row-major [.,4096] store, no bias (GEMM_S).
template <int EPI>
__global__ void __launch_bounds__(256)
gemm2_bt_kernel(const bf16* __restrict__ A, int lda,
                const bf16* __restrict__ Bt, int ldb, int K,
                const float* __restrict__ bias0, float* __restrict__ outS) {
  __shared__ __align__(16) bf16 As[128 * 32];
  __shared__ __align__(16) bf16 Bs[128 * 32];

  const int tid  = threadIdx.x;
  const int lane = tid & 63;
  const int wave = tid >> 6;
  const int wr = wave >> 1, wc = wave & 1;
  const int fr = lane & 15;
  const int fq = lane >> 4;
  const int row0 = blockIdx.y * 128;
  const int col0 = blockIdx.x * 128;

  const int li0 = tid, li1 = tid + 256;
  const int r0s = li0 >> 2, c0s = (li0 & 3) << 3;
  const int r1s = li1 >> 2, c1s = (li1 & 3) << 3;

  f32x4 acc[4][4] = {};

  for (int k0 = 0; k0 < K; k0 += 32) {
    gld_lds16(A  + (size_t)(row0 + r0s) * lda + k0 + c0s, &As[li0 * 8]);
    gld_lds16(Bt + (size_t)(col0 + r0s) * ldb + k0 + c0s, &Bs[li0 * 8]);
    gld_lds16(A  + (size_t)(row0 + r1s) * lda + k0 + c1s, &As[li1 * 8]);
    gld_lds16(Bt + (size_t)(col0 + r1s) * ldb + k0 + c1s, &Bs[li1 * 8]);
    __syncthreads();

    bf16x8 a[4], b[4];
#pragma unroll
    for (int m = 0; m < 4; ++m)
      a[m] = *reinterpret_cast<const bf16x8*>(&As[(wr * 64 + m * 16 + fr) * 32 + fq * 8]);
#pragma unroll
    for (int n = 0; n < 4; ++n)
      b[n] = *reinterpret_cast<const bf16x8*>(&Bs[(wc * 64 + n * 16 + fr) * 32 + fq * 8]);
#pragma unroll
    for (int m = 0; m < 4; ++m)
#pragma unroll
      for (int n = 0; n < 4; ++n)
        acc[m][n] = __builtin_amdgcn_mfma_f32_16x16x32_bf16(a[m], b[n], acc[m][n], 0, 0, 0);
    __syncthreads();
  }

#pragma unroll
  for (int m = 0; m < 4; ++m) {
#pragma unroll
    for (int n = 0; n < 4; ++n) {
      const int c = col0 + wc * 64 + n * 16 + fr;
      float bias = 0.f;
      if (EPI == 0) bias = bias0[c];
#pragma unroll
      for (int j = 0; j < 4; ++j) {
        const int r = row0 + wr * 64 + m * 16 + fq * 4 + j;
        if (EPI == 0)
          outS[((size_t)(r >> 4)) * (LS_ * M_) + (size_t)c * M_ + (r & 15)] = acc[m][n][j] + bias;
        else
          outS[(size_t)r * N1 + c] = acc[m][n][j];
      }
    }
  }
}

// ---------------------------------------------------------------------------
__global__ void rho_kernel(const bf16* __restrict__ h, const float* __restrict__ w2r,
                           const float* __restrict__ b2r, float* __restrict__ rho) {
  int r = blockIdx.x;
  int t = threadIdx.x;
  int lane = t & 63, wave = t >> 6;
  const bf16* hr = h + (size_t)r * N1 + H_;
  float s = 0.f;
#pragma unroll
  for (int j = 0; j < 8; ++j)
    s += __bfloat162float(hr[t * 8 + j]) * w2r[t * 8 + j];
#pragma unroll
  for (int off = 32; off > 0; off >>= 1) s += __shfl_down(s, off);
  __shared__ float ws4[4];
  if (lane == 0) ws4[wave] = s;
  __syncthreads();
  if (t == 0) rho[r] = ws4[0] + ws4[1] + ws4[2] + ws4[3] + b2r[0];
}

// ---------------------------------------------------------------------------
__global__ void finalize_kernel(const float* __restrict__ phi, const float* __restrict__ rho,
                                const float* __restrict__ etaMT, float* __restrict__ out0) {
  int i = blockIdx.x * blockDim.x + threadIdx.x;
  int b = i >> 10;
  const float* em = etaMT + (size_t)i * 16;
  const float* rb = rho + b * 16;
  float s = 0.f;
#pragma unroll
  for (int m = 0; m < 16; ++m) s += rb[m] * em[m];
  out0[i] = phi[i] - s;
}

// ---------------------------------------------------------------------------
extern "C" void kernel_launch(void* const* d_in, const int* in_sizes, int n_in,
                              void* d_out, int out_size, void* d_ws, size_t ws_size,
                              hipStream_t stream) {
  const float* phi = (const float*)d_in[0];
  const float* wMr = (const float*)d_in[1];
  const float* wMi = (const float*)d_in[2];
  const float* vM  = (const float*)d_in[3];
  const float* W1e = (const float*)d_in[4];
  const float* b1e = (const float*)d_in[5];
  const float* W2e = (const float*)d_in[6];
  const float* b2e = (const float*)d_in[7];
  const float* W1r = (const float*)d_in[8];
  const float* b1r = (const float*)d_in[9];
  const float* W2r = (const float*)d_in[10];
  const float* b2r = (const float*)d_in[11];

  float* out0 = (float*)d_out;            // phi_optimal [B, LS]
  float* out1 = out0 + (size_t)B_ * LS_;  // eta_M^T     [B, LS, M]

  bf16* Awr   = (bf16*)d_ws;                         // [4096, 2048]
  bf16* W1sT  = Awr  + (size_t)ROWS * KW;            // [4096, 2048]
  bf16* W1wT  = W1sT + (size_t)N1 * KW;              // [4096, 2048]
  bf16* h     = W1wT + (size_t)N1 * KW;              // [4096, 4096]
  bf16* W2t   = h + (size_t)ROWS * N1;               // [1024, 2048]
  bf16* sfeat = W2t + (size_t)LS_ * H_;              // [256, 2048]
  float* hS   = (float*)(sfeat + (size_t)B_ * 2048); // [256, 4096]
  float* hVT  = hS + (size_t)B_ * N1;                // [4096, 16]
  float* rho  = hVT + (size_t)N1 * 16;               // [4096]

  (void)hipFuncSetAttribute(reinterpret_cast<const void*>(gemm1_256_kernel),
                            hipFuncAttributeMaxDynamicSharedMemorySize, 131072);

  dim3 tb(32, 8);
  sfeat_kernel<<<(B_ * LS_) / 256, 256, 0, stream>>>(phi, sfeat);
  // W1sT: K-rows [0,2048) of (W1e | W1r)
  transpose_bf16_kernel<<<dim3(64, 64), tb, 0, stream>>>(W1e, W1sT, 2048, 2048);
  transpose_bf16_kernel<<<dim3(64, 64), tb, 0, stream>>>(W1r, W1sT + (size_t)2048 * 2048, 2048, 2048);
  // W1wT: K-rows [2048,4096)
  transpose_bf16_kernel<<<dim3(64, 64), tb, 0, stream>>>(W1e + (size_t)2048 * 2048, W1wT, 2048, 2048);
  transpose_bf16_kernel<<<dim3(64, 64), tb, 0, stream>>>(W1r + (size_t)2048 * 2048, W1wT + (size_t)2048 * 2048, 2048, 2048);
  transpose_bf16_kernel<<<dim3(LS_ / 32, H_ / 32), tb, 0, stream>>>(W2e, W2t, H_, LS_);

  build_awr_kernel<<<dim3(16, 256), 256, 0, stream>>>(wMr, wMi, Awr);
  hv_kernel<<<16, 256, 0, stream>>>(vM, W1e, W1r, hVT);

  // GEMM_S: hS = sfeat @ W1sT^T, [256 x 4096], K=2048
  gemm2_bt_kernel<1><<<dim3(N1 / 128, B_ / 128), 256, 0, stream>>>(
      sfeat, 2048, W1sT, KW, KW, nullptr, hS);

  // GEMM_W + fused epilogue: h = relu(Awr@W1wT^T + hS + hV + bias)
  gemm1_256_kernel<<<dim3(N1 / 256, ROWS / 256), 512, 131072, stream>>>(
      Awr, W1wT, b1e, b1r, hS, hVT, h);

  // GEMM2: eta_M^T scatter into out1, [4096 x 1024], K=2048
  gemm2_bt_kernel<0><<<dim3(LS_ / 128, ROWS / 128), 256, 0, stream>>>(
      h, N1, W2t, H_, H_, b2e, out1);

  rho_kernel<<<ROWS, 256, 0, stream>>>(h, W2r, b2r, rho);
  finalize_kernel<<<(B_ * LS_) / 256, 256, 0, stream>>>(phi, rho, out1, out0);
}

// Round 6
// 225.465 us; speedup vs baseline: 1.6340x; 1.6340x over previous
//
#include <hip/hip_runtime.h>
#include <hip/hip_bf16.h>
#include <stdint.h>

// Problem constants
#define B_    256
#define LS_   1024
#define LW_   1024
#define LV_   1024
#define M_    16
#define D_    5120
#define H_    2048
#define ROWS  4096   // B*M
#define N1    4096   // H (eta) + H (rho) fused
#define KW    2048   // K of the per-row (wr|wi) GEMM

typedef __hip_bfloat16 bf16;
typedef __bf16 bf16x8 __attribute__((ext_vector_type(8)));
typedef float f32x4 __attribute__((ext_vector_type(4)));

#define SB0() __builtin_amdgcn_sched_barrier(0)
#define LGKM(n) asm volatile("s_waitcnt lgkmcnt(" #n ")" ::: "memory")
#define VMC(n)  asm volatile("s_waitcnt vmcnt(" #n ")" ::: "memory")

// ---------------------------------------------------------------------------
// async global->LDS, 16B per lane (HW: wave-uniform LDS base + lane*16).
__device__ __forceinline__ void gld_lds16(const void* g, void* l) {
  auto gp = (const __attribute__((address_space(1))) uint32_t*)(uintptr_t)g;
  auto lp = (__attribute__((address_space(3))) uint32_t*)(uint32_t)(uintptr_t)l;
  __builtin_amdgcn_global_load_lds(gp, lp, 16, 0, 0);
}

// ---------------------------------------------------------------------------
__global__ void sfeat_kernel(const float* __restrict__ phi, bf16* __restrict__ sfeat) {
  int i = blockIdx.x * blockDim.x + threadIdx.x;
  int b = i >> 10, l = i & 1023;
  float p = phi[i];
  float s, c;
  sincosf(p, &s, &c);
  sfeat[b * 2048 + l]        = __float2bfloat16(0.03125f * c);
  sfeat[b * 2048 + 1024 + l] = __float2bfloat16(0.03125f * s);
}

// ---------------------------------------------------------------------------
// Transpose f32 [R,C] -> bf16 [C,R]
__global__ void transpose_bf16_kernel(const float* __restrict__ in, bf16* __restrict__ out,
                                      int R, int C) {
  __shared__ float tile[32][33];
  int c0 = blockIdx.x * 32, r0 = blockIdx.y * 32;
  int tx = threadIdx.x, ty = threadIdx.y;   // 32 x 8
#pragma unroll
  for (int i = 0; i < 32; i += 8)
    tile[ty + i][tx] = in[(size_t)(r0 + ty + i) * C + (c0 + tx)];
  __syncthreads();
#pragma unroll
  for (int i = 0; i < 32; i += 8)
    out[(size_t)(c0 + ty + i) * R + (r0 + tx)] = __float2bfloat16(tile[tx][ty + i]);
}

// ---------------------------------------------------------------------------
// Awr [4096, 2048] bf16: row r=b*16+m = [ wr[b,:,m] | wi[b,:,m] ]
__global__ void build_awr_kernel(const float* __restrict__ wr_, const float* __restrict__ wi_,
                                 bf16* __restrict__ Awr) {
  __shared__ float tr[64][17], ti[64][17];
  int b = blockIdx.y, l0 = blockIdx.x * 64;
  int t = threadIdx.x;   // 256
  const float* wrb = wr_ + (size_t)b * (LW_ * M_) + (size_t)l0 * 16;
  const float* wib = wi_ + (size_t)b * (LW_ * M_) + (size_t)l0 * 16;
#pragma unroll
  for (int i = 0; i < 4; ++i) {
    int e = i * 256 + t, l = e >> 4, m = e & 15;
    tr[l][m] = wrb[e];
    ti[l][m] = wib[e];
  }
  __syncthreads();
  int m = t >> 4, t4 = t & 15;    // 16 m x 16 l-quads
  bf16* outR = Awr + (size_t)(b * 16 + m) * KW + l0;
#pragma unroll
  for (int j = 0; j < 4; ++j) outR[t4 * 4 + j]        = __float2bfloat16(tr[t4 * 4 + j][m]);
#pragma unroll
  for (int j = 0; j < 4; ++j) outR[1024 + t4 * 4 + j] = __float2bfloat16(ti[t4 * 4 + j][m]);
}

// ---------------------------------------------------------------------------
// hVT [4096 n, 16 m] f32: hVT[n][m] = sum_l vM[l,m] * W1cat[4096+l, n]
// 256 blocks x 256 thr; one output per thread. Block g: 16 n-cols of
// W1e (g<128) or W1r (g>=128). LDS-staged 256-row chunks of vM and W.
__global__ void __launch_bounds__(256) hv_kernel(const float* __restrict__ vM,
                          const float* __restrict__ W1e, const float* __restrict__ W1r,
                          float* __restrict__ hVT) {
  __shared__ float vs[256][16];
  __shared__ float ws[256][16];
  const int t = threadIdx.x;
  const int g = blockIdx.x;                 // 0..255
  const float* Wb = (g < 128) ? W1e : W1r;
  const int nbase = (g & 127) * 16;         // column within Wb
  const int nout = ((g < 128) ? 0 : 2048) + nbase;
  const int m = t & 15, nl = t >> 4;
  float acc = 0.f;
  for (int l0 = 0; l0 < 1024; l0 += 256) {
    __syncthreads();
#pragma unroll
    for (int i = 0; i < 16; ++i) {
      int e = i * 256 + t, l = e >> 4, n = e & 15;
      vs[l][n] = vM[(size_t)(l0 + l) * 16 + n];
      ws[l][n] = Wb[(size_t)(4096 + l0 + l) * 2048 + nbase + n];
    }
    __syncthreads();
#pragma unroll 8
    for (int ll = 0; ll < 256; ++ll)
      acc += vs[ll][m] * ws[ll][nl];
  }
  hVT[(size_t)(nout + nl) * 16 + m] = acc;
}

// ---------------------------------------------------------------------------
// GEMM_W: 256x256 tile, BK=32, 8 waves (2Mx4N), 4-deep LDS ring, counted
// lgkmcnt pipeline, ONE barrier per K-tile (R4-proven schedule; K=2048).
// Epilogue fuses: h = relu(accW + hS[b,c] + hVT[c, r&15] + bias[c]) -> bf16.
__global__ void __launch_bounds__(512, 2)
gemm1_256_kernel(const bf16* __restrict__ A, const bf16* __restrict__ Bt,
                 const float* __restrict__ bias0, const float* __restrict__ bias1,
                 const float* __restrict__ hS, const float* __restrict__ hVT,
                 bf16* __restrict__ outH) {
  extern __shared__ __align__(16) char smem[];
  constexpr int NT = KW / 32;   // 64 K-tiles

  const int tid  = threadIdx.x;
  const int lane = tid & 63;
  const int wave = tid >> 6;
  const int wr = wave >> 2, wc = wave & 3;   // 2 x 4 wave grid, wave-tile 128x64
  const int fr = lane & 15, fq = lane >> 4;
  const int row0 = blockIdx.y * 256, col0 = blockIdx.x * 256;

  // fragment ds_read lane statics
  const int slotF = (((fr & 1) << 2) | fq) ^ ((fr >> 1) & 7);
  const int aOff = (wr << 13) + ((fr >> 1) << 7) + (slotF << 4);
  const int bOff = 16384 + (wc << 12) + ((fr >> 1) << 7) + (slotF << 4);

  // staging lane statics (two 8KB halves per operand)
  const int lg0 = (tid >> 3), lg1 = 64 + (tid >> 3);
  const int su0 = (tid & 7) ^ (lg0 & 7), su1 = (tid & 7) ^ (lg1 & 7);
  const int rowp0 = lg0 * 2 + (su0 >> 2), rowp1 = lg1 * 2 + (su1 >> 2);
  const int kb0 = (su0 & 3) << 4, kb1 = (su1 & 3) << 4;
  const char* pA0 = (const char*)A  + (size_t)(row0 + rowp0) * (KW * 2) + kb0;
  const char* pA1 = (const char*)A  + (size_t)(row0 + rowp1) * (KW * 2) + kb1;
  const char* pB0 = (const char*)Bt + (size_t)(col0 + rowp0) * (KW * 2) + kb0;
  const char* pB1 = (const char*)Bt + (size_t)(col0 + rowp1) * (KW * 2) + kb1;

  auto stageTile = [&](int T) {   // 4 gld per wave (vmcnt +4)
    char* dst = smem + (size_t)(T & 3) * 32768;
    const size_t ko = (size_t)T * 64;
    gld_lds16(pA0 + ko, dst + 0     + tid * 16);
    gld_lds16(pA1 + ko, dst + 8192  + tid * 16);
    gld_lds16(pB0 + ko, dst + 16384 + tid * 16);
    gld_lds16(pB1 + ko, dst + 24576 + tid * 16);
  };

  f32x4 acc[8][4] = {};
  bf16x8 bA[4], bB[4];

  // prologue: stage tiles 0,1,2; retire 0 (keep 2 flying); pre-read B(t0)
  stageTile(0); stageTile(1); stageTile(2);
  VMC(4);
  __builtin_amdgcn_s_barrier();
  {
    const char* bP = smem + bOff;   // buf0 B
#pragma unroll
    for (int n = 0; n < 4; ++n) bA[n] = *(const bf16x8*)(bP + n * 1024);
  }
  SB0();

  auto doIter = [&](int T, bf16x8 (&bCur)[4], bf16x8 (&bNxt)[4]) {
    const char* aP = smem + (size_t)(T & 3) * 32768 + aOff;
    const char* bP = smem + (size_t)((T + 1) & 3) * 32768 + bOff;
    bf16x8 a[8];
#pragma unroll
    for (int m = 0; m < 4; ++m) a[m] = *(const bf16x8*)(aP + m * 1024);
    SB0();
#pragma unroll
    for (int m = 4; m < 8; ++m) a[m] = *(const bf16x8*)(aP + m * 1024);
    SB0();
#pragma unroll
    for (int n = 0; n < 4; ++n) bNxt[n] = *(const bf16x8*)(bP + n * 1024);
    SB0();
    if (T + 3 < NT) stageTile(T + 3);
    SB0();
    LGKM(8);
    SB0();
    __builtin_amdgcn_s_setprio(1);
#pragma unroll
    for (int m = 0; m < 4; ++m)
#pragma unroll
      for (int n = 0; n < 4; ++n)
        acc[m][n] = __builtin_amdgcn_mfma_f32_16x16x32_bf16(a[m], bCur[n], acc[m][n], 0, 0, 0);
    SB0();
    LGKM(4);
    SB0();
#pragma unroll
    for (int m = 4; m < 8; ++m)
#pragma unroll
      for (int n = 0; n < 4; ++n)
        acc[m][n] = __builtin_amdgcn_mfma_f32_16x16x32_bf16(a[m], bCur[n], acc[m][n], 0, 0, 0);
    __builtin_amdgcn_s_setprio(0);
    SB0();
    LGKM(0);
    if (T + 3 < NT) { VMC(4); }
    else            { VMC(0); }
    __builtin_amdgcn_s_barrier();
  };

  for (int t = 0; t < NT - 2; t += 2) {
    doIter(t,     bA, bB);
    doIter(t + 1, bB, bA);
  }
  doIter(NT - 2, bA, bB);

  {  // final tile NT-1 (uses bB)
    const char* aP = smem + (size_t)((NT - 1) & 3) * 32768 + aOff;
    bf16x8 a[8];
#pragma unroll
    for (int m = 0; m < 4; ++m) a[m] = *(const bf16x8*)(aP + m * 1024);
    SB0();
#pragma unroll
    for (int m = 4; m < 8; ++m) a[m] = *(const bf16x8*)(aP + m * 1024);
    SB0();
    LGKM(4);
    SB0();
    __builtin_amdgcn_s_setprio(1);
#pragma unroll
    for (int m = 0; m < 4; ++m)
#pragma unroll
      for (int n = 0; n < 4; ++n)
        acc[m][n] = __builtin_amdgcn_mfma_f32_16x16x32_bf16(a[m], bB[n], acc[m][n], 0, 0, 0);
    SB0();
    LGKM(0);
    SB0();
#pragma unroll
    for (int m = 4; m < 8; ++m)
#pragma unroll
      for (int n = 0; n < 4; ++n)
        acc[m][n] = __builtin_amdgcn_mfma_f32_16x16x32_bf16(a[m], bB[n], acc[m][n], 0, 0, 0);
    __builtin_amdgcn_s_setprio(0);
  }

  // epilogue: h = relu(accW + hS[b,c] + hVT[c, fq*4+j] + bias[c])
#pragma unroll
  for (int n = 0; n < 4; ++n) {
    const int c = col0 + wc * 64 + n * 16 + fr;
    const float bias = (c < H_) ? bias0[c] : bias1[c - H_];
    const f32x4 hv = *(const f32x4*)&hVT[(size_t)c * 16 + fq * 4];
#pragma unroll
    for (int m = 0; m < 8; ++m) {
      const int rbase = row0 + wr * 128 + m * 16;
      const float hs = hS[(size_t)(rbase >> 4) * N1 + c];
#pragma unroll
      for (int j = 0; j < 4; ++j) {
        const int r = rbase + fq * 4 + j;
        float v = acc[m][n][j] + bias + hs + hv[j];
        outH[(size_t)r * N1 + c] = __float2bfloat16(v > 0.f ? v : 0.f);
      }
    }
  }
}

// ---------------------------------------------------------------------------
// 128x128 m97-style GEMM. EPI 0: eta^T scatter with bias. EPI 1: plain f32
// row-major [.,4096] store, no bias (GEMM_S).
template <int EPI>
__global__ void __launch_bounds__(256)
gemm2_bt_kernel(const bf16* __restrict__ A, int lda,
                const bf16* __restrict__ Bt, int ldb, int K,
                const float* __restrict__ bias0, float* __restrict__ outS) {
  __shared__ __align__(16) bf16 As[128 * 32];
  __shared__ __align__(16) bf16 Bs[128 * 32];

  const int tid  = threadIdx.x;
  const int lane = tid & 63;
  const int wave = tid >> 6;
  const int wr = wave >> 1, wc = wave & 1;
  const int fr = lane & 15;
  const int fq = lane >> 4;
  const int row0 = blockIdx.y * 128;
  const int col0 = blockIdx.x * 128;

  const int li0 = tid, li1 = tid + 256;
  const int r0s = li0 >> 2, c0s = (li0 & 3) << 3;
  const int r1s = li1 >> 2, c1s = (li1 & 3) << 3;

  f32x4 acc[4][4] = {};

  for (int k0 = 0; k0 < K; k0 += 32) {
    gld_lds16(A  + (size_t)(row0 + r0s) * lda + k0 + c0s, &As[li0 * 8]);
    gld_lds16(Bt + (size_t)(col0 + r0s) * ldb + k0 + c0s, &Bs[li0 * 8]);
    gld_lds16(A  + (size_t)(row0 + r1s) * lda + k0 + c1s, &As[li1 * 8]);
    gld_lds16(Bt + (size_t)(col0 + r1s) * ldb + k0 + c1s, &Bs[li1 * 8]);
    __syncthreads();

    bf16x8 a[4], b[4];
#pragma unroll
    for (int m = 0; m < 4; ++m)
      a[m] = *reinterpret_cast<const bf16x8*>(&As[(wr * 64 + m * 16 + fr) * 32 + fq * 8]);
#pragma unroll
    for (int n = 0; n < 4; ++n)
      b[n] = *reinterpret_cast<const bf16x8*>(&Bs[(wc * 64 + n * 16 + fr) * 32 + fq * 8]);
#pragma unroll
    for (int m = 0; m < 4; ++m)
#pragma unroll
      for (int n = 0; n < 4; ++n)
        acc[m][n] = __builtin_amdgcn_mfma_f32_16x16x32_bf16(a[m], b[n], acc[m][n], 0, 0, 0);
    __syncthreads();
  }

#pragma unroll
  for (int m = 0; m < 4; ++m) {
#pragma unroll
    for (int n = 0; n < 4; ++n) {
      const int c = col0 + wc * 64 + n * 16 + fr;
      float bias = 0.f;
      if (EPI == 0) bias = bias0[c];
#pragma unroll
      for (int j = 0; j < 4; ++j) {
        const int r = row0 + wr * 64 + m * 16 + fq * 4 + j;
        if (EPI == 0)
          outS[((size_t)(r >> 4)) * (LS_ * M_) + (size_t)c * M_ + (r & 15)] = acc[m][n][j] + bias;
        else
          outS[(size_t)r * N1 + c] = acc[m][n][j];
      }
    }
  }
}

// ---------------------------------------------------------------------------
__global__ void rho_kernel(const bf16* __restrict__ h, const float* __restrict__ w2r,
                           const float* __restrict__ b2r, float* __restrict__ rho) {
  int r = blockIdx.x;
  int t = threadIdx.x;
  int lane = t & 63, wave = t >> 6;
  const bf16* hr = h + (size_t)r * N1 + H_;
  float s = 0.f;
#pragma unroll
  for (int j = 0; j < 8; ++j)
    s += __bfloat162float(hr[t * 8 + j]) * w2r[t * 8 + j];
#pragma unroll
  for (int off = 32; off > 0; off >>= 1) s += __shfl_down(s, off);
  __shared__ float ws4[4];
  if (lane == 0) ws4[wave] = s;
  __syncthreads();
  if (t == 0) rho[r] = ws4[0] + ws4[1] + ws4[2] + ws4[3] + b2r[0];
}

// ---------------------------------------------------------------------------
__global__ void finalize_kernel(const float* __restrict__ phi, const float* __restrict__ rho,
                                const float* __restrict__ etaMT, float* __restrict__ out0) {
  int i = blockIdx.x * blockDim.x + threadIdx.x;
  int b = i >> 10;
  const float* em = etaMT + (size_t)i * 16;
  const float* rb = rho + b * 16;
  float s = 0.f;
#pragma unroll
  for (int m = 0; m < 16; ++m) s += rb[m] * em[m];
  out0[i] = phi[i] - s;
}

// ---------------------------------------------------------------------------
extern "C" void kernel_launch(void* const* d_in, const int* in_sizes, int n_in,
                              void* d_out, int out_size, void* d_ws, size_t ws_size,
                              hipStream_t stream) {
  const float* phi = (const float*)d_in[0];
  const float* wMr = (const float*)d_in[1];
  const float* wMi = (const float*)d_in[2];
  const float* vM  = (const float*)d_in[3];
  const float* W1e = (const float*)d_in[4];
  const float* b1e = (const float*)d_in[5];
  const float* W2e = (const float*)d_in[6];
  const float* b2e = (const float*)d_in[7];
  const float* W1r = (const float*)d_in[8];
  const float* b1r = (const float*)d_in[9];
  const float* W2r = (const float*)d_in[10];
  const float* b2r = (const float*)d_in[11];

  float* out0 = (float*)d_out;            // phi_optimal [B, LS]
  float* out1 = out0 + (size_t)B_ * LS_;  // eta_M^T     [B, LS, M]

  bf16* Awr   = (bf16*)d_ws;                         // [4096, 2048]
  bf16* W1sT  = Awr  + (size_t)ROWS * KW;            // [4096, 2048]
  bf16* W1wT  = W1sT + (size_t)N1 * KW;              // [4096, 2048]
  bf16* h     = W1wT + (size_t)N1 * KW;              // [4096, 4096]
  bf16* W2t   = h + (size_t)ROWS * N1;               // [1024, 2048]
  bf16* sfeat = W2t + (size_t)LS_ * H_;              // [256, 2048]
  float* hS   = (float*)(sfeat + (size_t)B_ * 2048); // [256, 4096]
  float* hVT  = hS + (size_t)B_ * N1;                // [4096, 16]
  float* rho  = hVT + (size_t)N1 * 16;               // [4096]

  (void)hipFuncSetAttribute(reinterpret_cast<const void*>(gemm1_256_kernel),
                            hipFuncAttributeMaxDynamicSharedMemorySize, 131072);

  dim3 tb(32, 8);
  sfeat_kernel<<<(B_ * LS_) / 256, 256, 0, stream>>>(phi, sfeat);
  // W1sT: K-rows [0,2048) of (W1e | W1r)
  transpose_bf16_kernel<<<dim3(64, 64), tb, 0, stream>>>(W1e, W1sT, 2048, 2048);
  transpose_bf16_kernel<<<dim3(64, 64), tb, 0, stream>>>(W1r, W1sT + (size_t)2048 * 2048, 2048, 2048);
  // W1wT: K-rows [2048,4096)
  transpose_bf16_kernel<<<dim3(64, 64), tb, 0, stream>>>(W1e + (size_t)2048 * 2048, W1wT, 2048, 2048);
  transpose_bf16_kernel<<<dim3(64, 64), tb, 0, stream>>>(W1r + (size_t)2048 * 2048, W1wT + (size_t)2048 * 2048, 2048, 2048);
  transpose_bf16_kernel<<<dim3(LS_ / 32, H_ / 32), tb, 0, stream>>>(W2e, W2t, H_, LS_);

  build_awr_kernel<<<dim3(16, 256), 256, 0, stream>>>(wMr, wMi, Awr);
  hv_kernel<<<256, 256, 0, stream>>>(vM, W1e, W1r, hVT);

  // GEMM_S: hS = sfeat @ W1sT^T, [256 x 4096], K=2048
  gemm2_bt_kernel<1><<<dim3(N1 / 128, B_ / 128), 256, 0, stream>>>(
      sfeat, 2048, W1sT, KW, KW, nullptr, hS);

  // GEMM_W + fused epilogue: h = relu(Awr@W1wT^T + hS + hV + bias)
  gemm1_256_kernel<<<dim3(N1 / 256, ROWS / 256), 512, 131072, stream>>>(
      Awr, W1wT, b1e, b1r, hS, hVT, h);

  // GEMM2: eta_M^T scatter into out1, [4096 x 1024], K=2048
  gemm2_bt_kernel<0><<<dim3(LS_ / 128, ROWS / 128), 256, 0, stream>>>(
      h, N1, W2t, H_, H_, b2e, out1);

  rho_kernel<<<ROWS, 256, 0, stream>>>(h, W2r, b2r, rho);
  finalize_kernel<<<(B_ * LS_) / 256, 256, 0, stream>>>(phi, rho, out1, out0);
}

// Round 7
// 183.749 us; speedup vs baseline: 2.0049x; 1.2270x over previous
//
#include <hip/hip_runtime.h>
#include <hip/hip_bf16.h>
#include <stdint.h>

// Problem constants
#define B_    256
#define LS_   1024
#define LW_   1024
#define LV_   1024
#define M_    16
#define D_    5120
#define H_    2048
#define ROWS  4096   // B*M
#define N1    4096   // H (eta) + H (rho) fused
#define KW    2048   // K of the per-row (wr|wi) GEMM

typedef __hip_bfloat16 bf16;
typedef __bf16 bf16x8 __attribute__((ext_vector_type(8)));
typedef float f32x4 __attribute__((ext_vector_type(4)));

#define SB0() __builtin_amdgcn_sched_barrier(0)
#define LGKM(n) asm volatile("s_waitcnt lgkmcnt(" #n ")" ::: "memory")
#define VMC(n)  asm volatile("s_waitcnt vmcnt(" #n ")" ::: "memory")

// ---------------------------------------------------------------------------
// async global->LDS, 16B per lane (HW: wave-uniform LDS base + lane*16).
__device__ __forceinline__ void gld_lds16(const void* g, void* l) {
  auto gp = (const __attribute__((address_space(1))) uint32_t*)(uintptr_t)g;
  auto lp = (__attribute__((address_space(3))) uint32_t*)(uint32_t)(uintptr_t)l;
  __builtin_amdgcn_global_load_lds(gp, lp, 16, 0, 0);
}

// ---------------------------------------------------------------------------
__global__ void sfeat_kernel(const float* __restrict__ phi, bf16* __restrict__ sfeat) {
  int i = blockIdx.x * blockDim.x + threadIdx.x;
  int b = i >> 10, l = i & 1023;
  float p = phi[i];
  float s, c;
  sincosf(p, &s, &c);
  sfeat[b * 2048 + l]        = __float2bfloat16(0.03125f * c);
  sfeat[b * 2048 + 1024 + l] = __float2bfloat16(0.03125f * s);
}

// ---------------------------------------------------------------------------
// Transpose f32 [R,C] -> bf16 [C,R]
__global__ void transpose_bf16_kernel(const float* __restrict__ in, bf16* __restrict__ out,
                                      int R, int C) {
  __shared__ float tile[32][33];
  int c0 = blockIdx.x * 32, r0 = blockIdx.y * 32;
  int tx = threadIdx.x, ty = threadIdx.y;   // 32 x 8
#pragma unroll
  for (int i = 0; i < 32; i += 8)
    tile[ty + i][tx] = in[(size_t)(r0 + ty + i) * C + (c0 + tx)];
  __syncthreads();
#pragma unroll
  for (int i = 0; i < 32; i += 8)
    out[(size_t)(c0 + ty + i) * R + (r0 + tx)] = __float2bfloat16(tile[tx][ty + i]);
}

// ---------------------------------------------------------------------------
// Awr [4096, 2048] bf16: row r=b*16+m = [ wr[b,:,m] | wi[b,:,m] ]
__global__ void build_awr_kernel(const float* __restrict__ wr_, const float* __restrict__ wi_,
                                 bf16* __restrict__ Awr) {
  __shared__ float tr[64][17], ti[64][17];
  int b = blockIdx.y, l0 = blockIdx.x * 64;
  int t = threadIdx.x;   // 256
  const float* wrb = wr_ + (size_t)b * (LW_ * M_) + (size_t)l0 * 16;
  const float* wib = wi_ + (size_t)b * (LW_ * M_) + (size_t)l0 * 16;
#pragma unroll
  for (int i = 0; i < 4; ++i) {
    int e = i * 256 + t, l = e >> 4, m = e & 15;
    tr[l][m] = wrb[e];
    ti[l][m] = wib[e];
  }
  __syncthreads();
  int m = t >> 4, t4 = t & 15;    // 16 m x 16 l-quads
  bf16* outR = Awr + (size_t)(b * 16 + m) * KW + l0;
#pragma unroll
  for (int j = 0; j < 4; ++j) outR[t4 * 4 + j]        = __float2bfloat16(tr[t4 * 4 + j][m]);
#pragma unroll
  for (int j = 0; j < 4; ++j) outR[1024 + t4 * 4 + j] = __float2bfloat16(ti[t4 * 4 + j][m]);
}

// ---------------------------------------------------------------------------
// hVT [4096 n, 16 m] f32: hVT[n][m] = sum_l vM[l,m] * W1cat[4096+l, n]
__global__ void __launch_bounds__(256) hv_kernel(const float* __restrict__ vM,
                          const float* __restrict__ W1e, const float* __restrict__ W1r,
                          float* __restrict__ hVT) {
  __shared__ float vs[256][16];
  __shared__ float ws[256][16];
  const int t = threadIdx.x;
  const int g = blockIdx.x;                 // 0..255
  const float* Wb = (g < 128) ? W1e : W1r;
  const int nbase = (g & 127) * 16;
  const int nout = ((g < 128) ? 0 : 2048) + nbase;
  const int m = t & 15, nl = t >> 4;
  float acc = 0.f;
  for (int l0 = 0; l0 < 1024; l0 += 256) {
    __syncthreads();
#pragma unroll
    for (int i = 0; i < 16; ++i) {
      int e = i * 256 + t, l = e >> 4, n = e & 15;
      vs[l][n] = vM[(size_t)(l0 + l) * 16 + n];
      ws[l][n] = Wb[(size_t)(4096 + l0 + l) * 2048 + nbase + n];
    }
    __syncthreads();
#pragma unroll 8
    for (int ll = 0; ll < 256; ++ll)
      acc += vs[ll][m] * ws[ll][nl];
  }
  hVT[(size_t)(nout + nl) * 16 + m] = acc;
}

// ---------------------------------------------------------------------------
// GEMM_W: 256x256 tile, BK=32, 8 waves, 4-deep LDS ring, counted lgkmcnt
// pipeline (R4-proven). Epilogue: h = relu(acc + hS + hVT + bias) -> bf16.
__global__ void __launch_bounds__(512, 2)
gemm1_256_kernel(const bf16* __restrict__ A, const bf16* __restrict__ Bt,
                 const float* __restrict__ bias0, const float* __restrict__ bias1,
                 const float* __restrict__ hS, const float* __restrict__ hVT,
                 bf16* __restrict__ outH) {
  extern __shared__ __align__(16) char smem[];
  constexpr int NT = KW / 32;   // 64 K-tiles

  const int tid  = threadIdx.x;
  const int lane = tid & 63;
  const int wave = tid >> 6;
  const int wr = wave >> 2, wc = wave & 3;   // 2 x 4 wave grid, wave-tile 128x64
  const int fr = lane & 15, fq = lane >> 4;
  const int row0 = blockIdx.y * 256, col0 = blockIdx.x * 256;

  const int slotF = (((fr & 1) << 2) | fq) ^ ((fr >> 1) & 7);
  const int aOff = (wr << 13) + ((fr >> 1) << 7) + (slotF << 4);
  const int bOff = 16384 + (wc << 12) + ((fr >> 1) << 7) + (slotF << 4);

  const int lg0 = (tid >> 3), lg1 = 64 + (tid >> 3);
  const int su0 = (tid & 7) ^ (lg0 & 7), su1 = (tid & 7) ^ (lg1 & 7);
  const int rowp0 = lg0 * 2 + (su0 >> 2), rowp1 = lg1 * 2 + (su1 >> 2);
  const int kb0 = (su0 & 3) << 4, kb1 = (su1 & 3) << 4;
  const char* pA0 = (const char*)A  + (size_t)(row0 + rowp0) * (KW * 2) + kb0;
  const char* pA1 = (const char*)A  + (size_t)(row0 + rowp1) * (KW * 2) + kb1;
  const char* pB0 = (const char*)Bt + (size_t)(col0 + rowp0) * (KW * 2) + kb0;
  const char* pB1 = (const char*)Bt + (size_t)(col0 + rowp1) * (KW * 2) + kb1;

  auto stageTile = [&](int T) {   // 4 gld per wave
    char* dst = smem + (size_t)(T & 3) * 32768;
    const size_t ko = (size_t)T * 64;
    gld_lds16(pA0 + ko, dst + 0     + tid * 16);
    gld_lds16(pA1 + ko, dst + 8192  + tid * 16);
    gld_lds16(pB0 + ko, dst + 16384 + tid * 16);
    gld_lds16(pB1 + ko, dst + 24576 + tid * 16);
  };

  f32x4 acc[8][4] = {};
  bf16x8 bA[4], bB[4];

  stageTile(0); stageTile(1); stageTile(2);
  VMC(4);
  __builtin_amdgcn_s_barrier();
  {
    const char* bP = smem + bOff;
#pragma unroll
    for (int n = 0; n < 4; ++n) bA[n] = *(const bf16x8*)(bP + n * 1024);
  }
  SB0();

  auto doIter = [&](int T, bf16x8 (&bCur)[4], bf16x8 (&bNxt)[4]) {
    const char* aP = smem + (size_t)(T & 3) * 32768 + aOff;
    const char* bP = smem + (size_t)((T + 1) & 3) * 32768 + bOff;
    bf16x8 a[8];
#pragma unroll
    for (int m = 0; m < 4; ++m) a[m] = *(const bf16x8*)(aP + m * 1024);
    SB0();
#pragma unroll
    for (int m = 4; m < 8; ++m) a[m] = *(const bf16x8*)(aP + m * 1024);
    SB0();
#pragma unroll
    for (int n = 0; n < 4; ++n) bNxt[n] = *(const bf16x8*)(bP + n * 1024);
    SB0();
    if (T + 3 < NT) stageTile(T + 3);
    SB0();
    LGKM(8);
    SB0();
    __builtin_amdgcn_s_setprio(1);
#pragma unroll
    for (int m = 0; m < 4; ++m)
#pragma unroll
      for (int n = 0; n < 4; ++n)
        acc[m][n] = __builtin_amdgcn_mfma_f32_16x16x32_bf16(a[m], bCur[n], acc[m][n], 0, 0, 0);
    SB0();
    LGKM(4);
    SB0();
#pragma unroll
    for (int m = 4; m < 8; ++m)
#pragma unroll
      for (int n = 0; n < 4; ++n)
        acc[m][n] = __builtin_amdgcn_mfma_f32_16x16x32_bf16(a[m], bCur[n], acc[m][n], 0, 0, 0);
    __builtin_amdgcn_s_setprio(0);
    SB0();
    LGKM(0);
    if (T + 3 < NT) { VMC(4); }
    else            { VMC(0); }
    __builtin_amdgcn_s_barrier();
  };

  for (int t = 0; t < NT - 2; t += 2) {
    doIter(t,     bA, bB);
    doIter(t + 1, bB, bA);
  }
  doIter(NT - 2, bA, bB);

  {  // final tile NT-1 (uses bB)
    const char* aP = smem + (size_t)((NT - 1) & 3) * 32768 + aOff;
    bf16x8 a[8];
#pragma unroll
    for (int m = 0; m < 4; ++m) a[m] = *(const bf16x8*)(aP + m * 1024);
    SB0();
#pragma unroll
    for (int m = 4; m < 8; ++m) a[m] = *(const bf16x8*)(aP + m * 1024);
    SB0();
    LGKM(4);
    SB0();
    __builtin_amdgcn_s_setprio(1);
#pragma unroll
    for (int m = 0; m < 4; ++m)
#pragma unroll
      for (int n = 0; n < 4; ++n)
        acc[m][n] = __builtin_amdgcn_mfma_f32_16x16x32_bf16(a[m], bB[n], acc[m][n], 0, 0, 0);
    SB0();
    LGKM(0);
    SB0();
#pragma unroll
    for (int m = 4; m < 8; ++m)
#pragma unroll
      for (int n = 0; n < 4; ++n)
        acc[m][n] = __builtin_amdgcn_mfma_f32_16x16x32_bf16(a[m], bB[n], acc[m][n], 0, 0, 0);
    __builtin_amdgcn_s_setprio(0);
  }

  // epilogue: h = relu(acc + hS[b,c] + hVT[c, fq*4+j] + bias[c])
#pragma unroll
  for (int n = 0; n < 4; ++n) {
    const int c = col0 + wc * 64 + n * 16 + fr;
    const float bias = (c < H_) ? bias0[c] : bias1[c - H_];
    const f32x4 hv = *(const f32x4*)&hVT[(size_t)c * 16 + fq * 4];
#pragma unroll
    for (int m = 0; m < 8; ++m) {
      const int rbase = row0 + wr * 128 + m * 16;
      const float hs = hS[(size_t)(rbase >> 4) * N1 + c];
#pragma unroll
      for (int j = 0; j < 4; ++j) {
        const int r = rbase + fq * 4 + j;
        float v = acc[m][n][j] + bias + hs + hv[j];
        outH[(size_t)r * N1 + c] = __float2bfloat16(v > 0.f ? v : 0.f);
      }
    }
  }
}

// ---------------------------------------------------------------------------
// gemm128_pipe: 128x128 tile, BK=32, 4 waves (2x2, wave-tile 64x64), 4-deep
// LDS ring, counted pipeline — same schedule/swizzle algebra as gemm1 with
// halved constants (4 gld/tile, 8 ds_reads/iter, LGKM(4) covers the cluster).
// K fixed at 2048 (NT=64); lda/ldb runtime (elements).
// EPI 0 (GEMM2/eta): outS = eta_M^T scatter (acc+bias); etaB[b,c] =
//   sum_m rho[b*16+m]*(acc+bias) via in-lane FMA + shfl_xor(16/32).
// EPI 1 (GEMM_S): hS f32 row-major [., N1] store, no bias.
template <int EPI>
__global__ void __launch_bounds__(256, 2)
gemm128_pipe_kernel(const bf16* __restrict__ A, int lda,
                    const bf16* __restrict__ Bt, int ldb,
                    const float* __restrict__ bias0, const float* __restrict__ rho,
                    float* __restrict__ outS, float* __restrict__ etaB) {
  extern __shared__ __align__(16) char smem[];
  constexpr int NT = 64;   // K = 2048

  const int tid  = threadIdx.x;
  const int lane = tid & 63;
  const int wave = tid >> 6;                 // 0..3
  const int wr = wave >> 1, wc = wave & 1;   // 2x2 wave grid
  const int fr = lane & 15, fq = lane >> 4;
  const int row0 = blockIdx.y * 128, col0 = blockIdx.x * 128;

  const int slotF = (((fr & 1) << 2) | fq) ^ ((fr >> 1) & 7);
  const int aOff = (wr << 12) + ((fr >> 1) << 7) + (slotF << 4);
  const int bOff = 8192 + (wc << 12) + ((fr >> 1) << 7) + (slotF << 4);

  const int lgl = tid >> 3;                        // line within half (0..31)
  const int su  = (tid & 7) ^ (lgl & 7);           // (32+lgl)&7 == lgl&7
  const int rp0 = lgl * 2 + (su >> 2);             // rows 0..63
  const int rp1 = (32 + lgl) * 2 + (su >> 2);      // rows 64..127
  const int kb  = (su & 3) << 4;
  const char* pA0 = (const char*)A  + (size_t)(row0 + rp0) * ((size_t)lda * 2) + kb;
  const char* pA1 = (const char*)A  + (size_t)(row0 + rp1) * ((size_t)lda * 2) + kb;
  const char* pB0 = (const char*)Bt + (size_t)(col0 + rp0) * ((size_t)ldb * 2) + kb;
  const char* pB1 = (const char*)Bt + (size_t)(col0 + rp1) * ((size_t)ldb * 2) + kb;

  auto stageTile = [&](int T) {   // 4 gld per wave
    char* dst = smem + (size_t)(T & 3) * 16384;
    const size_t ko = (size_t)T * 64;
    gld_lds16(pA0 + ko, dst + 0     + tid * 16);
    gld_lds16(pA1 + ko, dst + 4096  + tid * 16);
    gld_lds16(pB0 + ko, dst + 8192  + tid * 16);
    gld_lds16(pB1 + ko, dst + 12288 + tid * 16);
  };

  f32x4 acc[4][4] = {};
  bf16x8 bA[4], bB[4];

  stageTile(0); stageTile(1); stageTile(2);
  VMC(4);
  __builtin_amdgcn_s_barrier();
  {
    const char* bP = smem + bOff;
#pragma unroll
    for (int n = 0; n < 4; ++n) bA[n] = *(const bf16x8*)(bP + n * 1024);
  }
  SB0();

  auto doIter = [&](int T, bf16x8 (&bCur)[4], bf16x8 (&bNxt)[4]) {
    const char* aP = smem + (size_t)(T & 3) * 16384 + aOff;
    const char* bP = smem + (size_t)((T + 1) & 3) * 16384 + bOff;
    bf16x8 a[4];
#pragma unroll
    for (int m = 0; m < 4; ++m) a[m] = *(const bf16x8*)(aP + m * 1024);
    SB0();
#pragma unroll
    for (int n = 0; n < 4; ++n) bNxt[n] = *(const bf16x8*)(bP + n * 1024);
    SB0();
    if (T + 3 < NT) stageTile(T + 3);
    SB0();
    LGKM(4);                     // a[0..3] landed; bNxt may still fly
    SB0();
    __builtin_amdgcn_s_setprio(1);
#pragma unroll
    for (int m = 0; m < 4; ++m)
#pragma unroll
      for (int n = 0; n < 4; ++n)
        acc[m][n] = __builtin_amdgcn_mfma_f32_16x16x32_bf16(a[m], bCur[n], acc[m][n], 0, 0, 0);
    __builtin_amdgcn_s_setprio(0);
    SB0();
    LGKM(0);
    if (T + 3 < NT) { VMC(4); }
    else            { VMC(0); }
    __builtin_amdgcn_s_barrier();
  };

  for (int t = 0; t < NT - 2; t += 2) {
    doIter(t,     bA, bB);
    doIter(t + 1, bB, bA);
  }
  doIter(NT - 2, bA, bB);

  {  // final tile NT-1 (uses bB)
    const char* aP = smem + (size_t)((NT - 1) & 3) * 16384 + aOff;
    bf16x8 a[4];
#pragma unroll
    for (int m = 0; m < 4; ++m) a[m] = *(const bf16x8*)(aP + m * 1024);
    SB0();
    LGKM(0);
    SB0();
    __builtin_amdgcn_s_setprio(1);
#pragma unroll
    for (int m = 0; m < 4; ++m)
#pragma unroll
      for (int n = 0; n < 4; ++n)
        acc[m][n] = __builtin_amdgcn_mfma_f32_16x16x32_bf16(a[m], bB[n], acc[m][n], 0, 0, 0);
    __builtin_amdgcn_s_setprio(0);
  }

  if (EPI == 0) {
#pragma unroll
    for (int m = 0; m < 4; ++m) {
      const int bg = (row0 >> 4) + wr * 4 + m;                 // batch index
      const f32x4 rv = *(const f32x4*)&rho[bg * 16 + fq * 4];
#pragma unroll
      for (int n = 0; n < 4; ++n) {
        const int c = col0 + wc * 64 + n * 16 + fr;
        const float bias = bias0[c];
        float part = 0.f;
#pragma unroll
        for (int j = 0; j < 4; ++j) {
          float v = acc[m][n][j] + bias;
          outS[(size_t)bg * (LS_ * M_) + (size_t)c * M_ + (fq * 4 + j)] = v;
          part += rv[j] * v;
        }
        part += __shfl_xor(part, 16);
        part += __shfl_xor(part, 32);
        if (fq == 0) etaB[(size_t)bg * LS_ + c] = part;
      }
    }
  } else {
#pragma unroll
    for (int m = 0; m < 4; ++m) {
#pragma unroll
      for (int n = 0; n < 4; ++n) {
        const int c = col0 + wc * 64 + n * 16 + fr;
#pragma unroll
        for (int j = 0; j < 4; ++j) {
          const int r = row0 + wr * 64 + m * 16 + fq * 4 + j;
          outS[(size_t)r * N1 + c] = acc[m][n][j];
        }
      }
    }
  }
}

// ---------------------------------------------------------------------------
__global__ void rho_kernel(const bf16* __restrict__ h, const float* __restrict__ w2r,
                           const float* __restrict__ b2r, float* __restrict__ rho) {
  int r = blockIdx.x;
  int t = threadIdx.x;
  int lane = t & 63, wave = t >> 6;
  const bf16* hr = h + (size_t)r * N1 + H_;
  float s = 0.f;
#pragma unroll
  for (int j = 0; j < 8; ++j)
    s += __bfloat162float(hr[t * 8 + j]) * w2r[t * 8 + j];
#pragma unroll
  for (int off = 32; off > 0; off >>= 1) s += __shfl_down(s, off);
  __shared__ float ws4[4];
  if (lane == 0) ws4[wave] = s;
  __syncthreads();
  if (t == 0) rho[r] = ws4[0] + ws4[1] + ws4[2] + ws4[3] + b2r[0];
}

// ---------------------------------------------------------------------------
__global__ void finalize_lite_kernel(const float* __restrict__ phi,
                                     const float* __restrict__ etaB,
                                     float* __restrict__ out0) {
  int i = blockIdx.x * blockDim.x + threadIdx.x;
  out0[i] = phi[i] - etaB[i];
}

// ---------------------------------------------------------------------------
extern "C" void kernel_launch(void* const* d_in, const int* in_sizes, int n_in,
                              void* d_out, int out_size, void* d_ws, size_t ws_size,
                              hipStream_t stream) {
  const float* phi = (const float*)d_in[0];
  const float* wMr = (const float*)d_in[1];
  const float* wMi = (const float*)d_in[2];
  const float* vM  = (const float*)d_in[3];
  const float* W1e = (const float*)d_in[4];
  const float* b1e = (const float*)d_in[5];
  const float* W2e = (const float*)d_in[6];
  const float* b2e = (const float*)d_in[7];
  const float* W1r = (const float*)d_in[8];
  const float* b1r = (const float*)d_in[9];
  const float* W2r = (const float*)d_in[10];
  const float* b2r = (const float*)d_in[11];

  float* out0 = (float*)d_out;            // phi_optimal [B, LS]
  float* out1 = out0 + (size_t)B_ * LS_;  // eta_M^T     [B, LS, M]

  bf16* Awr   = (bf16*)d_ws;                         // [4096, 2048]
  bf16* W1sT  = Awr  + (size_t)ROWS * KW;            // [4096, 2048]
  bf16* W1wT  = W1sT + (size_t)N1 * KW;              // [4096, 2048]
  bf16* h     = W1wT + (size_t)N1 * KW;              // [4096, 4096]
  bf16* W2t   = h + (size_t)ROWS * N1;               // [1024, 2048]
  bf16* sfeat = W2t + (size_t)LS_ * H_;              // [256, 2048]
  float* hS   = (float*)(sfeat + (size_t)B_ * 2048); // [256, 4096]
  float* hVT  = hS + (size_t)B_ * N1;                // [4096, 16]
  float* rho  = hVT + (size_t)N1 * 16;               // [4096]
  float* etaB = rho + ROWS;                          // [256, 1024]

  (void)hipFuncSetAttribute(reinterpret_cast<const void*>(gemm1_256_kernel),
                            hipFuncAttributeMaxDynamicSharedMemorySize, 131072);
  (void)hipFuncSetAttribute(reinterpret_cast<const void*>(gemm128_pipe_kernel<0>),
                            hipFuncAttributeMaxDynamicSharedMemorySize, 65536);
  (void)hipFuncSetAttribute(reinterpret_cast<const void*>(gemm128_pipe_kernel<1>),
                            hipFuncAttributeMaxDynamicSharedMemorySize, 65536);

  dim3 tb(32, 8);
  sfeat_kernel<<<(B_ * LS_) / 256, 256, 0, stream>>>(phi, sfeat);
  // W1sT: K-rows [0,2048) of (W1e | W1r)
  transpose_bf16_kernel<<<dim3(64, 64), tb, 0, stream>>>(W1e, W1sT, 2048, 2048);
  transpose_bf16_kernel<<<dim3(64, 64), tb, 0, stream>>>(W1r, W1sT + (size_t)2048 * 2048, 2048, 2048);
  // W1wT: K-rows [2048,4096)
  transpose_bf16_kernel<<<dim3(64, 64), tb, 0, stream>>>(W1e + (size_t)2048 * 2048, W1wT, 2048, 2048);
  transpose_bf16_kernel<<<dim3(64, 64), tb, 0, stream>>>(W1r + (size_t)2048 * 2048, W1wT + (size_t)2048 * 2048, 2048, 2048);
  transpose_bf16_kernel<<<dim3(LS_ / 32, H_ / 32), tb, 0, stream>>>(W2e, W2t, H_, LS_);

  build_awr_kernel<<<dim3(16, 256), 256, 0, stream>>>(wMr, wMi, Awr);
  hv_kernel<<<256, 256, 0, stream>>>(vM, W1e, W1r, hVT);

  // GEMM_S: hS = sfeat @ W1sT^T, [256 x 4096], K=2048
  gemm128_pipe_kernel<1><<<dim3(N1 / 128, B_ / 128), 256, 65536, stream>>>(
      sfeat, 2048, W1sT, KW, nullptr, nullptr, hS, nullptr);

  // GEMM_W + fused epilogue: h = relu(Awr@W1wT^T + hS + hV + bias)
  gemm1_256_kernel<<<dim3(N1 / 256, ROWS / 256), 512, 131072, stream>>>(
      Awr, W1wT, b1e, b1r, hS, hVT, h);

  // rho before GEMM2 (depends only on h)
  rho_kernel<<<ROWS, 256, 0, stream>>>(h, W2r, b2r, rho);

  // GEMM2: out1 scatter + fused eta contraction, [4096 x 1024], K=2048
  gemm128_pipe_kernel<0><<<dim3(LS_ / 128, ROWS / 128), 256, 65536, stream>>>(
      h, N1, W2t, H_, b2e, rho, out1, etaB);

  finalize_lite_kernel<<<(B_ * LS_) / 256, 256, 0, stream>>>(phi, etaB, out0);
}

// Round 8
// 182.365 us; speedup vs baseline: 2.0201x; 1.0076x over previous
//
#include <hip/hip_runtime.h>
#include <hip/hip_bf16.h>
#include <stdint.h>

// Problem constants
#define B_    256
#define LS_   1024
#define LW_   1024
#define LV_   1024
#define M_    16
#define D_    5120
#define H_    2048
#define ROWS  4096   // B*M
#define N1    4096   // H (eta) + H (rho) fused
#define KW    2048   // K of the per-row (wr|wi) GEMM

typedef __hip_bfloat16 bf16;
typedef __bf16 bf16x8 __attribute__((ext_vector_type(8)));
typedef __bf16 bf16x4 __attribute__((ext_vector_type(4)));
typedef float f32x4 __attribute__((ext_vector_type(4)));

#define SB0() __builtin_amdgcn_sched_barrier(0)
#define LGKM(n) asm volatile("s_waitcnt lgkmcnt(" #n ")" ::: "memory")
#define VMC(n)  asm volatile("s_waitcnt vmcnt(" #n ")" ::: "memory")

// ---------------------------------------------------------------------------
// async global->LDS, 16B per lane (HW: wave-uniform LDS base + lane*16).
__device__ __forceinline__ void gld_lds16(const void* g, void* l) {
  auto gp = (const __attribute__((address_space(1))) uint32_t*)(uintptr_t)g;
  auto lp = (__attribute__((address_space(3))) uint32_t*)(uint32_t)(uintptr_t)l;
  __builtin_amdgcn_global_load_lds(gp, lp, 16, 0, 0);
}

// ---------------------------------------------------------------------------
__global__ void sfeat_kernel(const float* __restrict__ phi, bf16* __restrict__ sfeat) {
  int i = blockIdx.x * blockDim.x + threadIdx.x;
  int b = i >> 10, l = i & 1023;
  float p = phi[i];
  float s, c;
  sincosf(p, &s, &c);
  sfeat[b * 2048 + l]        = __float2bfloat16(0.03125f * c);
  sfeat[b * 2048 + 1024 + l] = __float2bfloat16(0.03125f * s);
}

// ---------------------------------------------------------------------------
// 64x64-tile f32 -> bf16 transpose core. in [R,C] row-major, out [C,R].
// float4 loads (16B/lane), bf16x4 stores (8B/lane); LDS conflicts <=2-way.
__device__ __forceinline__ void transpose64_body(const float* __restrict__ in,
                                                 bf16* __restrict__ out,
                                                 int C, int R, int r0, int c0, int t) {
  __shared__ float tile[64][65];
  const int tx = t & 15, ty = t >> 4;   // 16 x 16
#pragma unroll
  for (int i = 0; i < 4; ++i) {
    const float4 v = *(const float4*)&in[(size_t)(r0 + ty + i * 16) * C + c0 + tx * 4];
    tile[ty + i * 16][tx * 4 + 0] = v.x;
    tile[ty + i * 16][tx * 4 + 1] = v.y;
    tile[ty + i * 16][tx * 4 + 2] = v.z;
    tile[ty + i * 16][tx * 4 + 3] = v.w;
  }
  __syncthreads();
#pragma unroll
  for (int i = 0; i < 4; ++i) {
    const int n = c0 + ty + i * 16;
    bf16x4 o;
#pragma unroll
    for (int j = 0; j < 4; ++j) o[j] = (__bf16)tile[tx * 4 + j][ty + i * 16];
    *(bf16x4*)&out[(size_t)n * R + r0 + tx * 4] = o;
  }
}

// Four 2048x2048 W1 transpose jobs in one launch (grid 32x32x4).
__global__ void __launch_bounds__(256)
transpose_w1_kernel(const float* __restrict__ W1e, const float* __restrict__ W1r,
                    bf16* __restrict__ W1sT, bf16* __restrict__ W1wT) {
  const int z = blockIdx.z;
  const float* src = (z == 0 || z == 2) ? W1e : W1r;
  src += (z < 2) ? 0 : (size_t)2048 * 2048;          // K-rows [0,2048) vs [2048,4096)
  bf16* dst = (z < 2) ? W1sT : W1wT;
  dst += (z == 0 || z == 2) ? 0 : (size_t)2048 * 2048;
  transpose64_body(src, dst, 2048, 2048, blockIdx.y * 64, blockIdx.x * 64, threadIdx.x);
}

// Generic single transpose (W2e [2048,1024] -> W2t [1024,2048]).
__global__ void __launch_bounds__(256)
transpose_one_kernel(const float* __restrict__ in, bf16* __restrict__ out, int R, int C) {
  transpose64_body(in, out, C, R, blockIdx.y * 64, blockIdx.x * 64, threadIdx.x);
}

// ---------------------------------------------------------------------------
// Awr [4096, 2048] bf16: row r=b*16+m = [ wr[b,:,m] | wi[b,:,m] ]
__global__ void build_awr_kernel(const float* __restrict__ wr_, const float* __restrict__ wi_,
                                 bf16* __restrict__ Awr) {
  __shared__ float tr[64][17], ti[64][17];
  int b = blockIdx.y, l0 = blockIdx.x * 64;
  int t = threadIdx.x;   // 256
  const float* wrb = wr_ + (size_t)b * (LW_ * M_) + (size_t)l0 * 16;
  const float* wib = wi_ + (size_t)b * (LW_ * M_) + (size_t)l0 * 16;
#pragma unroll
  for (int i = 0; i < 4; ++i) {
    int e = i * 256 + t, l = e >> 4, m = e & 15;
    tr[l][m] = wrb[e];
    ti[l][m] = wib[e];
  }
  __syncthreads();
  int m = t >> 4, t4 = t & 15;    // 16 m x 16 l-quads
  bf16* outR = Awr + (size_t)(b * 16 + m) * KW + l0;
#pragma unroll
  for (int j = 0; j < 4; ++j) outR[t4 * 4 + j]        = __float2bfloat16(tr[t4 * 4 + j][m]);
#pragma unroll
  for (int j = 0; j < 4; ++j) outR[1024 + t4 * 4 + j] = __float2bfloat16(ti[t4 * 4 + j][m]);
}

// ---------------------------------------------------------------------------
// hVT [4096 n, 16 m] f32: hVT[n][m] = sum_l vM[l,m] * W1cat[4096+l, n]
__global__ void __launch_bounds__(256) hv_kernel(const float* __restrict__ vM,
                          const float* __restrict__ W1e, const float* __restrict__ W1r,
                          float* __restrict__ hVT) {
  __shared__ float vs[256][16];
  __shared__ float ws[256][16];
  const int t = threadIdx.x;
  const int g = blockIdx.x;                 // 0..255
  const float* Wb = (g < 128) ? W1e : W1r;
  const int nbase = (g & 127) * 16;
  const int nout = ((g < 128) ? 0 : 2048) + nbase;
  const int m = t & 15, nl = t >> 4;
  float acc = 0.f;
  for (int l0 = 0; l0 < 1024; l0 += 256) {
    __syncthreads();
#pragma unroll
    for (int i = 0; i < 16; ++i) {
      int e = i * 256 + t, l = e >> 4, n = e & 15;
      vs[l][n] = vM[(size_t)(l0 + l) * 16 + n];
      ws[l][n] = Wb[(size_t)(4096 + l0 + l) * 2048 + nbase + n];
    }
    __syncthreads();
#pragma unroll 8
    for (int ll = 0; ll < 256; ++ll)
      acc += vs[ll][m] * ws[ll][nl];
  }
  hVT[(size_t)(nout + nl) * 16 + m] = acc;
}

// ---------------------------------------------------------------------------
// GEMM_W: 256x256 tile, BK=32, 8 waves, 4-deep LDS ring, counted lgkmcnt
// pipeline (R4-proven). Epilogue: h = relu(acc + SUM4(hSp) + hVT + bias).
__global__ void __launch_bounds__(512, 2)
gemm1_256_kernel(const bf16* __restrict__ A, const bf16* __restrict__ Bt,
                 const float* __restrict__ bias0, const float* __restrict__ bias1,
                 const float* __restrict__ hSp, const float* __restrict__ hVT,
                 bf16* __restrict__ outH) {
  extern __shared__ __align__(16) char smem[];
  constexpr int NT = KW / 32;   // 64 K-tiles

  const int tid  = threadIdx.x;
  const int lane = tid & 63;
  const int wave = tid >> 6;
  const int wr = wave >> 2, wc = wave & 3;   // 2 x 4 wave grid, wave-tile 128x64
  const int fr = lane & 15, fq = lane >> 4;
  const int row0 = blockIdx.y * 256, col0 = blockIdx.x * 256;

  const int slotF = (((fr & 1) << 2) | fq) ^ ((fr >> 1) & 7);
  const int aOff = (wr << 13) + ((fr >> 1) << 7) + (slotF << 4);
  const int bOff = 16384 + (wc << 12) + ((fr >> 1) << 7) + (slotF << 4);

  const int lg0 = (tid >> 3), lg1 = 64 + (tid >> 3);
  const int su0 = (tid & 7) ^ (lg0 & 7), su1 = (tid & 7) ^ (lg1 & 7);
  const int rowp0 = lg0 * 2 + (su0 >> 2), rowp1 = lg1 * 2 + (su1 >> 2);
  const int kb0 = (su0 & 3) << 4, kb1 = (su1 & 3) << 4;
  const char* pA0 = (const char*)A  + (size_t)(row0 + rowp0) * (KW * 2) + kb0;
  const char* pA1 = (const char*)A  + (size_t)(row0 + rowp1) * (KW * 2) + kb1;
  const char* pB0 = (const char*)Bt + (size_t)(col0 + rowp0) * (KW * 2) + kb0;
  const char* pB1 = (const char*)Bt + (size_t)(col0 + rowp1) * (KW * 2) + kb1;

  auto stageTile = [&](int T) {   // 4 gld per wave
    char* dst = smem + (size_t)(T & 3) * 32768;
    const size_t ko = (size_t)T * 64;
    gld_lds16(pA0 + ko, dst + 0     + tid * 16);
    gld_lds16(pA1 + ko, dst + 8192  + tid * 16);
    gld_lds16(pB0 + ko, dst + 16384 + tid * 16);
    gld_lds16(pB1 + ko, dst + 24576 + tid * 16);
  };

  f32x4 acc[8][4] = {};
  bf16x8 bA[4], bB[4];

  stageTile(0); stageTile(1); stageTile(2);
  VMC(4);
  __builtin_amdgcn_s_barrier();
  {
    const char* bP = smem + bOff;
#pragma unroll
    for (int n = 0; n < 4; ++n) bA[n] = *(const bf16x8*)(bP + n * 1024);
  }
  SB0();

  auto doIter = [&](int T, bf16x8 (&bCur)[4], bf16x8 (&bNxt)[4]) {
    const char* aP = smem + (size_t)(T & 3) * 32768 + aOff;
    const char* bP = smem + (size_t)((T + 1) & 3) * 32768 + bOff;
    bf16x8 a[8];
#pragma unroll
    for (int m = 0; m < 4; ++m) a[m] = *(const bf16x8*)(aP + m * 1024);
    SB0();
#pragma unroll
    for (int m = 4; m < 8; ++m) a[m] = *(const bf16x8*)(aP + m * 1024);
    SB0();
#pragma unroll
    for (int n = 0; n < 4; ++n) bNxt[n] = *(const bf16x8*)(bP + n * 1024);
    SB0();
    if (T + 3 < NT) stageTile(T + 3);
    SB0();
    LGKM(8);
    SB0();
    __builtin_amdgcn_s_setprio(1);
#pragma unroll
    for (int m = 0; m < 4; ++m)
#pragma unroll
      for (int n = 0; n < 4; ++n)
        acc[m][n] = __builtin_amdgcn_mfma_f32_16x16x32_bf16(a[m], bCur[n], acc[m][n], 0, 0, 0);
    SB0();
    LGKM(4);
    SB0();
#pragma unroll
    for (int m = 4; m < 8; ++m)
#pragma unroll
      for (int n = 0; n < 4; ++n)
        acc[m][n] = __builtin_amdgcn_mfma_f32_16x16x32_bf16(a[m], bCur[n], acc[m][n], 0, 0, 0);
    __builtin_amdgcn_s_setprio(0);
    SB0();
    LGKM(0);
    if (T + 3 < NT) { VMC(4); }
    else            { VMC(0); }
    __builtin_amdgcn_s_barrier();
  };

  for (int t = 0; t < NT - 2; t += 2) {
    doIter(t,     bA, bB);
    doIter(t + 1, bB, bA);
  }
  doIter(NT - 2, bA, bB);

  {  // final tile NT-1 (uses bB)
    const char* aP = smem + (size_t)((NT - 1) & 3) * 32768 + aOff;
    bf16x8 a[8];
#pragma unroll
    for (int m = 0; m < 4; ++m) a[m] = *(const bf16x8*)(aP + m * 1024);
    SB0();
#pragma unroll
    for (int m = 4; m < 8; ++m) a[m] = *(const bf16x8*)(aP + m * 1024);
    SB0();
    LGKM(4);
    SB0();
    __builtin_amdgcn_s_setprio(1);
#pragma unroll
    for (int m = 0; m < 4; ++m)
#pragma unroll
      for (int n = 0; n < 4; ++n)
        acc[m][n] = __builtin_amdgcn_mfma_f32_16x16x32_bf16(a[m], bB[n], acc[m][n], 0, 0, 0);
    SB0();
    LGKM(0);
    SB0();
#pragma unroll
    for (int m = 4; m < 8; ++m)
#pragma unroll
      for (int n = 0; n < 4; ++n)
        acc[m][n] = __builtin_amdgcn_mfma_f32_16x16x32_bf16(a[m], bB[n], acc[m][n], 0, 0, 0);
    __builtin_amdgcn_s_setprio(0);
  }

  // epilogue: h = relu(acc + sum4(hSp) + hVT[c, fq*4+j] + bias[c])
#pragma unroll
  for (int n = 0; n < 4; ++n) {
    const int c = col0 + wc * 64 + n * 16 + fr;
    const float bias = (c < H_) ? bias0[c] : bias1[c - H_];
    const f32x4 hv = *(const f32x4*)&hVT[(size_t)c * 16 + fq * 4];
#pragma unroll
    for (int m = 0; m < 8; ++m) {
      const int rbase = row0 + wr * 128 + m * 16;
      const float* hp = hSp + (size_t)(rbase >> 4) * N1 + c;
      const float hs = hp[0] + hp[(size_t)B_ * N1] + hp[(size_t)2 * B_ * N1] + hp[(size_t)3 * B_ * N1];
#pragma unroll
      for (int j = 0; j < 4; ++j) {
        const int r = rbase + fq * 4 + j;
        float v = acc[m][n][j] + bias + hs + hv[j];
        outH[(size_t)r * N1 + c] = __float2bfloat16(v > 0.f ? v : 0.f);
      }
    }
  }
}

// ---------------------------------------------------------------------------
// gemm128_pipe: 128x128 tile, BK=32, 4 waves (2x2, wave-tile 64x64), 4-deep
// LDS ring, counted pipeline (R7-proven). Template NT (K = NT*32).
// EPI 0 (GEMM2): outS = eta_M^T scatter (acc+bias); fused eta contraction ->
//   out0[b,c] = phi[b,c] - sum_m rho*(acc+bias) via FMA + shfl_xor(16/32).
// EPI 1 (GEMM_S split-K): z = blockIdx.z selects K-slice of 512 and partial
//   output buffer; plain f32 [., N1] store.
template <int EPI, int NT>
__global__ void __launch_bounds__(256, 2)
gemm128_pipe_kernel(const bf16* __restrict__ A, int lda,
                    const bf16* __restrict__ Bt, int ldb,
                    const float* __restrict__ bias0, const float* __restrict__ rho,
                    const float* __restrict__ phi,
                    float* __restrict__ outS, float* __restrict__ out0) {
  extern __shared__ __align__(16) char smem[];

  if (EPI == 1) {
    const int z = blockIdx.z;
    A    += (size_t)z * 512;
    Bt   += (size_t)z * 512;
    outS += (size_t)z * ((size_t)B_ * N1);
  }

  const int tid  = threadIdx.x;
  const int lane = tid & 63;
  const int wave = tid >> 6;                 // 0..3
  const int wr = wave >> 1, wc = wave & 1;   // 2x2 wave grid
  const int fr = lane & 15, fq = lane >> 4;
  const int row0 = blockIdx.y * 128, col0 = blockIdx.x * 128;

  const int slotF = (((fr & 1) << 2) | fq) ^ ((fr >> 1) & 7);
  const int aOff = (wr << 12) + ((fr >> 1) << 7) + (slotF << 4);
  const int bOff = 8192 + (wc << 12) + ((fr >> 1) << 7) + (slotF << 4);

  const int lgl = tid >> 3;                        // line within half (0..31)
  const int su  = (tid & 7) ^ (lgl & 7);
  const int rp0 = lgl * 2 + (su >> 2);             // rows 0..63
  const int rp1 = (32 + lgl) * 2 + (su >> 2);      // rows 64..127
  const int kb  = (su & 3) << 4;
  const char* pA0 = (const char*)A  + (size_t)(row0 + rp0) * ((size_t)lda * 2) + kb;
  const char* pA1 = (const char*)A  + (size_t)(row0 + rp1) * ((size_t)lda * 2) + kb;
  const char* pB0 = (const char*)Bt + (size_t)(col0 + rp0) * ((size_t)ldb * 2) + kb;
  const char* pB1 = (const char*)Bt + (size_t)(col0 + rp1) * ((size_t)ldb * 2) + kb;

  auto stageTile = [&](int T) {   // 4 gld per wave
    char* dst = smem + (size_t)(T & 3) * 16384;
    const size_t ko = (size_t)T * 64;
    gld_lds16(pA0 + ko, dst + 0     + tid * 16);
    gld_lds16(pA1 + ko, dst + 4096  + tid * 16);
    gld_lds16(pB0 + ko, dst + 8192  + tid * 16);
    gld_lds16(pB1 + ko, dst + 12288 + tid * 16);
  };

  f32x4 acc[4][4] = {};
  bf16x8 bA[4], bB[4];

  stageTile(0); stageTile(1); stageTile(2);
  VMC(4);
  __builtin_amdgcn_s_barrier();
  {
    const char* bP = smem + bOff;
#pragma unroll
    for (int n = 0; n < 4; ++n) bA[n] = *(const bf16x8*)(bP + n * 1024);
  }
  SB0();

  auto doIter = [&](int T, bf16x8 (&bCur)[4], bf16x8 (&bNxt)[4]) {
    const char* aP = smem + (size_t)(T & 3) * 16384 + aOff;
    const char* bP = smem + (size_t)((T + 1) & 3) * 16384 + bOff;
    bf16x8 a[4];
#pragma unroll
    for (int m = 0; m < 4; ++m) a[m] = *(const bf16x8*)(aP + m * 1024);
    SB0();
#pragma unroll
    for (int n = 0; n < 4; ++n) bNxt[n] = *(const bf16x8*)(bP + n * 1024);
    SB0();
    if (T + 3 < NT) stageTile(T + 3);
    SB0();
    LGKM(4);                     // a[0..3] landed; bNxt may still fly
    SB0();
    __builtin_amdgcn_s_setprio(1);
#pragma unroll
    for (int m = 0; m < 4; ++m)
#pragma unroll
      for (int n = 0; n < 4; ++n)
        acc[m][n] = __builtin_amdgcn_mfma_f32_16x16x32_bf16(a[m], bCur[n], acc[m][n], 0, 0, 0);
    __builtin_amdgcn_s_setprio(0);
    SB0();
    LGKM(0);
    if (T + 3 < NT) { VMC(4); }
    else            { VMC(0); }
    __builtin_amdgcn_s_barrier();
  };

  for (int t = 0; t < NT - 2; t += 2) {
    doIter(t,     bA, bB);
    doIter(t + 1, bB, bA);
  }
  doIter(NT - 2, bA, bB);

  {  // final tile NT-1 (uses bB)
    const char* aP = smem + (size_t)((NT - 1) & 3) * 16384 + aOff;
    bf16x8 a[4];
#pragma unroll
    for (int m = 0; m < 4; ++m) a[m] = *(const bf16x8*)(aP + m * 1024);
    SB0();
    LGKM(0);
    SB0();
    __builtin_amdgcn_s_setprio(1);
#pragma unroll
    for (int m = 0; m < 4; ++m)
#pragma unroll
      for (int n = 0; n < 4; ++n)
        acc[m][n] = __builtin_amdgcn_mfma_f32_16x16x32_bf16(a[m], bB[n], acc[m][n], 0, 0, 0);
    __builtin_amdgcn_s_setprio(0);
  }

  if (EPI == 0) {
#pragma unroll
    for (int m = 0; m < 4; ++m) {
      const int bg = (row0 >> 4) + wr * 4 + m;                 // batch index
      const f32x4 rv = *(const f32x4*)&rho[bg * 16 + fq * 4];
#pragma unroll
      for (int n = 0; n < 4; ++n) {
        const int c = col0 + wc * 64 + n * 16 + fr;
        const float bias = bias0[c];
        float part = 0.f;
#pragma unroll
        for (int j = 0; j < 4; ++j) {
          float v = acc[m][n][j] + bias;
          outS[(size_t)bg * (LS_ * M_) + (size_t)c * M_ + (fq * 4 + j)] = v;
          part += rv[j] * v;
        }
        part += __shfl_xor(part, 16);
        part += __shfl_xor(part, 32);
        if (fq == 0)
          out0[(size_t)bg * LS_ + c] = phi[(size_t)bg * LS_ + c] - part;
      }
    }
  } else {
#pragma unroll
    for (int m = 0; m < 4; ++m) {
#pragma unroll
      for (int n = 0; n < 4; ++n) {
        const int c = col0 + wc * 64 + n * 16 + fr;
#pragma unroll
        for (int j = 0; j < 4; ++j) {
          const int r = row0 + wr * 64 + m * 16 + fq * 4 + j;
          outS[(size_t)r * N1 + c] = acc[m][n][j];
        }
      }
    }
  }
}

// ---------------------------------------------------------------------------
__global__ void rho_kernel(const bf16* __restrict__ h, const float* __restrict__ w2r,
                           const float* __restrict__ b2r, float* __restrict__ rho) {
  int r = blockIdx.x;
  int t = threadIdx.x;
  int lane = t & 63, wave = t >> 6;
  const bf16* hr = h + (size_t)r * N1 + H_;
  float s = 0.f;
#pragma unroll
  for (int j = 0; j < 8; ++j)
    s += __bfloat162float(hr[t * 8 + j]) * w2r[t * 8 + j];
#pragma unroll
  for (int off = 32; off > 0; off >>= 1) s += __shfl_down(s, off);
  __shared__ float ws4[4];
  if (lane == 0) ws4[wave] = s;
  __syncthreads();
  if (t == 0) rho[r] = ws4[0] + ws4[1] + ws4[2] + ws4[3] + b2r[0];
}

// ---------------------------------------------------------------------------
extern "C" void kernel_launch(void* const* d_in, const int* in_sizes, int n_in,
                              void* d_out, int out_size, void* d_ws, size_t ws_size,
                              hipStream_t stream) {
  const float* phi = (const float*)d_in[0];
  const float* wMr = (const float*)d_in[1];
  const float* wMi = (const float*)d_in[2];
  const float* vM  = (const float*)d_in[3];
  const float* W1e = (const float*)d_in[4];
  const float* b1e = (const float*)d_in[5];
  const float* W2e = (const float*)d_in[6];
  const float* b2e = (const float*)d_in[7];
  const float* W1r = (const float*)d_in[8];
  const float* b1r = (const float*)d_in[9];
  const float* W2r = (const float*)d_in[10];
  const float* b2r = (const float*)d_in[11];

  float* out0 = (float*)d_out;            // phi_optimal [B, LS]
  float* out1 = out0 + (size_t)B_ * LS_;  // eta_M^T     [B, LS, M]

  bf16* Awr   = (bf16*)d_ws;                         // [4096, 2048]
  bf16* W1sT  = Awr  + (size_t)ROWS * KW;            // [4096, 2048]
  bf16* W1wT  = W1sT + (size_t)N1 * KW;              // [4096, 2048]
  bf16* h     = W1wT + (size_t)N1 * KW;              // [4096, 4096]
  bf16* W2t   = h + (size_t)ROWS * N1;               // [1024, 2048]
  bf16* sfeat = W2t + (size_t)LS_ * H_;              // [256, 2048]
  float* hSp  = (float*)(sfeat + (size_t)B_ * 2048); // 4 x [256, 4096] partials
  float* hVT  = hSp + (size_t)4 * B_ * N1;           // [4096, 16]
  float* rho  = hVT + (size_t)N1 * 16;               // [4096]

  (void)hipFuncSetAttribute(reinterpret_cast<const void*>(gemm1_256_kernel),
                            hipFuncAttributeMaxDynamicSharedMemorySize, 131072);
  (void)hipFuncSetAttribute(reinterpret_cast<const void*>(gemm128_pipe_kernel<0, 64>),
                            hipFuncAttributeMaxDynamicSharedMemorySize, 65536);
  (void)hipFuncSetAttribute(reinterpret_cast<const void*>(gemm128_pipe_kernel<1, 16>),
                            hipFuncAttributeMaxDynamicSharedMemorySize, 65536);

  sfeat_kernel<<<(B_ * LS_) / 256, 256, 0, stream>>>(phi, sfeat);
  // all four W1 transposes in one launch
  transpose_w1_kernel<<<dim3(32, 32, 4), 256, 0, stream>>>(W1e, W1r, W1sT, W1wT);
  transpose_one_kernel<<<dim3(LS_ / 64, H_ / 64), 256, 0, stream>>>(W2e, W2t, H_, LS_);

  build_awr_kernel<<<dim3(16, 256), 256, 0, stream>>>(wMr, wMi, Awr);
  hv_kernel<<<256, 256, 0, stream>>>(vM, W1e, W1r, hVT);

  // GEMM_S split-K x4: hSp[z] = sfeat @ W1sT[:, z*512:(z+1)*512]^T
  gemm128_pipe_kernel<1, 16><<<dim3(N1 / 128, B_ / 128, 4), 256, 65536, stream>>>(
      sfeat, 2048, W1sT, KW, nullptr, nullptr, nullptr, hSp, nullptr);

  // GEMM_W + fused epilogue: h = relu(Awr@W1wT^T + sum(hSp) + hV + bias)
  gemm1_256_kernel<<<dim3(N1 / 256, ROWS / 256), 512, 131072, stream>>>(
      Awr, W1wT, b1e, b1r, hSp, hVT, h);

  // rho before GEMM2 (depends only on h)
  rho_kernel<<<ROWS, 256, 0, stream>>>(h, W2r, b2r, rho);

  // GEMM2: out1 scatter + fused eta contraction + out0 = phi - eta
  gemm128_pipe_kernel<0, 64><<<dim3(LS_ / 128, ROWS / 128), 256, 65536, stream>>>(
      h, N1, W2t, H_, b2e, rho, phi, out1, out0);
}

// Round 9
// 148.713 us; speedup vs baseline: 2.4772x; 1.2263x over previous
//
#include <hip/hip_runtime.h>
#include <hip/hip_bf16.h>
#include <stdint.h>

// Problem constants
#define B_    256
#define LS_   1024
#define LW_   1024
#define LV_   1024
#define M_    16
#define D_    5120
#define H_    2048
#define ROWS  4096   // B*M
#define N1    4096   // H (eta) + H (rho) fused
#define KW    2048   // K of the per-row (wr|wi) GEMM

typedef __hip_bfloat16 bf16;
typedef __bf16 bf16x8 __attribute__((ext_vector_type(8)));
typedef __bf16 bf16x4 __attribute__((ext_vector_type(4)));
typedef float f32x4 __attribute__((ext_vector_type(4)));

#define SB0() __builtin_amdgcn_sched_barrier(0)
#define LGKM(n) asm volatile("s_waitcnt lgkmcnt(" #n ")" ::: "memory")
#define VMC(n)  asm volatile("s_waitcnt vmcnt(" #n ")" ::: "memory")

// ---------------------------------------------------------------------------
// async global->LDS, 16B per lane (HW: wave-uniform LDS base + lane*16).
__device__ __forceinline__ void gld_lds16(const void* g, void* l) {
  auto gp = (const __attribute__((address_space(1))) uint32_t*)(uintptr_t)g;
  auto lp = (__attribute__((address_space(3))) uint32_t*)(uint32_t)(uintptr_t)l;
  __builtin_amdgcn_global_load_lds(gp, lp, 16, 0, 0);
}

// ---------------------------------------------------------------------------
// Merged preprocessing kernel: one launch, block-range dispatch.
//   [0,256)          hv      : hVT[n][m] = sum_l vM[l,m]*W1cat[4096+l,n]
//   [256,4352)       tw1     : four 2048x2048 W1 f32->bf16 transposes
//   [4352,4864)      tw2     : W2e [2048,1024] -> W2t [1024,2048]
//   [4864,8960)      awr     : Awr[b*16+m] = [wr[b,:,m] | wi[b,:,m]]
//   [8960,9984)      sfeat   : [B,2048] = [mag*cos | mag*sin]
__device__ __forceinline__ void transpose64_body(char* sm, const float* __restrict__ in,
                                                 bf16* __restrict__ out,
                                                 int C, int R, int r0, int c0, int t) {
  float (*tile)[65] = (float (*)[65])sm;
  const int tx = t & 15, ty = t >> 4;   // 16 x 16
#pragma unroll
  for (int i = 0; i < 4; ++i) {
    const float4 v = *(const float4*)&in[(size_t)(r0 + ty + i * 16) * C + c0 + tx * 4];
    tile[ty + i * 16][tx * 4 + 0] = v.x;
    tile[ty + i * 16][tx * 4 + 1] = v.y;
    tile[ty + i * 16][tx * 4 + 2] = v.z;
    tile[ty + i * 16][tx * 4 + 3] = v.w;
  }
  __syncthreads();
#pragma unroll
  for (int i = 0; i < 4; ++i) {
    const int n = c0 + ty + i * 16;
    bf16x4 o;
#pragma unroll
    for (int j = 0; j < 4; ++j) o[j] = (__bf16)tile[tx * 4 + j][ty + i * 16];
    *(bf16x4*)&out[(size_t)n * R + r0 + tx * 4] = o;
  }
}

__global__ void __launch_bounds__(256)
prep_kernel(const float* __restrict__ phi,
            const float* __restrict__ wMr, const float* __restrict__ wMi,
            const float* __restrict__ vM,
            const float* __restrict__ W1e, const float* __restrict__ W1r,
            const float* __restrict__ W2e,
            bf16* __restrict__ sfeat, bf16* __restrict__ Awr,
            bf16* __restrict__ W1sT, bf16* __restrict__ W1wT,
            bf16* __restrict__ W2t, float* __restrict__ hVT) {
  __shared__ __align__(16) char sm[32768];
  const int bid = blockIdx.x;
  const int t = threadIdx.x;

  if (bid < 256) {
    // ---- hv ----
    float (*vs)[16] = (float (*)[16])sm;
    float (*ws)[16] = (float (*)[16])(sm + 16384);
    const float* Wb = (bid < 128) ? W1e : W1r;
    const int nbase = (bid & 127) * 16;
    const int nout = ((bid < 128) ? 0 : 2048) + nbase;
    const int m = t & 15, nl = t >> 4;
    float acc = 0.f;
    for (int l0 = 0; l0 < 1024; l0 += 256) {
      __syncthreads();
#pragma unroll
      for (int i = 0; i < 16; ++i) {
        int e = i * 256 + t, l = e >> 4, n = e & 15;
        vs[l][n] = vM[(size_t)(l0 + l) * 16 + n];
        ws[l][n] = Wb[(size_t)(4096 + l0 + l) * 2048 + nbase + n];
      }
      __syncthreads();
#pragma unroll 8
      for (int ll = 0; ll < 256; ++ll)
        acc += vs[ll][m] * ws[ll][nl];
    }
    hVT[(size_t)(nout + nl) * 16 + m] = acc;
  } else if (bid < 4352) {
    // ---- tw1: four 2048x2048 transposes ----
    const int idx = bid - 256;
    const int z = idx >> 10, rem = idx & 1023;
    const float* src = (z == 0 || z == 2) ? W1e : W1r;
    src += (z < 2) ? 0 : (size_t)2048 * 2048;
    bf16* dst = (z < 2) ? W1sT : W1wT;
    dst += (z == 0 || z == 2) ? 0 : (size_t)2048 * 2048;
    transpose64_body(sm, src, dst, 2048, 2048, (rem >> 5) * 64, (rem & 31) * 64, t);
  } else if (bid < 4864) {
    // ---- tw2: W2e [2048,1024] -> W2t ----
    const int idx = bid - 4352;
    transpose64_body(sm, W2e, W2t, LS_, H_, (idx >> 4) * 64, (idx & 15) * 64, t);
  } else if (bid < 8960) {
    // ---- awr ----
    const int idx = bid - 4864;
    const int b = idx >> 4, l0 = (idx & 15) * 64;
    float (*tr)[17] = (float (*)[17])sm;
    float (*ti)[17] = (float (*)[17])(sm + 4352 * 4);
    const float* wrb = wMr + (size_t)b * (LW_ * M_) + (size_t)l0 * 16;
    const float* wib = wMi + (size_t)b * (LW_ * M_) + (size_t)l0 * 16;
#pragma unroll
    for (int i = 0; i < 4; ++i) {
      int e = i * 256 + t, l = e >> 4, m = e & 15;
      tr[l][m] = wrb[e];
      ti[l][m] = wib[e];
    }
    __syncthreads();
    int m = t >> 4, t4 = t & 15;
    bf16* outR = Awr + (size_t)(b * 16 + m) * KW + l0;
#pragma unroll
    for (int j = 0; j < 4; ++j) outR[t4 * 4 + j]        = __float2bfloat16(tr[t4 * 4 + j][m]);
#pragma unroll
    for (int j = 0; j < 4; ++j) outR[1024 + t4 * 4 + j] = __float2bfloat16(ti[t4 * 4 + j][m]);
  } else {
    // ---- sfeat ----
    const int i = (bid - 8960) * 256 + t;
    const int b = i >> 10, l = i & 1023;
    float p = phi[i];
    float s, c;
    sincosf(p, &s, &c);
    sfeat[b * 2048 + l]        = __float2bfloat16(0.03125f * c);
    sfeat[b * 2048 + 1024 + l] = __float2bfloat16(0.03125f * s);
  }
}

// ---------------------------------------------------------------------------
// hS2[b,c] = sum_z hSp[z][b,c] + bias[c]   (bias = b1e | b1r split at H_)
__global__ void __launch_bounds__(256)
hsum_kernel(const float* __restrict__ hSp, const float* __restrict__ b1e,
            const float* __restrict__ b1r, float* __restrict__ hS2) {
  const int i = (blockIdx.x * 256 + threadIdx.x) * 4;
  const int c = i & (N1 - 1);
  f32x4 v = *(const f32x4*)&hSp[i];
  v = v + *(const f32x4*)&hSp[(size_t)B_ * N1 + i];
  v = v + *(const f32x4*)&hSp[(size_t)2 * B_ * N1 + i];
  v = v + *(const f32x4*)&hSp[(size_t)3 * B_ * N1 + i];
  const float* bp = (c < H_) ? &b1e[c] : &b1r[c - H_];
  v = v + *(const f32x4*)bp;
  *(f32x4*)&hS2[i] = v;
}

// ---------------------------------------------------------------------------
// GEMM_W: 256x256 tile, BK=32, 8 waves, 4-deep LDS ring, counted lgkmcnt
// pipeline (R4-proven). Epilogue: h = relu(acc + hS2[b,c] + hVT[c,m]) (bias
// already folded into hS2).
__global__ void __launch_bounds__(512, 2)
gemm1_256_kernel(const bf16* __restrict__ A, const bf16* __restrict__ Bt,
                 const float* __restrict__ hS2, const float* __restrict__ hVT,
                 bf16* __restrict__ outH) {
  extern __shared__ __align__(16) char smem[];
  constexpr int NT = KW / 32;   // 64 K-tiles

  const int tid  = threadIdx.x;
  const int lane = tid & 63;
  const int wave = tid >> 6;
  const int wr = wave >> 2, wc = wave & 3;   // 2 x 4 wave grid, wave-tile 128x64
  const int fr = lane & 15, fq = lane >> 4;
  const int row0 = blockIdx.y * 256, col0 = blockIdx.x * 256;

  const int slotF = (((fr & 1) << 2) | fq) ^ ((fr >> 1) & 7);
  const int aOff = (wr << 13) + ((fr >> 1) << 7) + (slotF << 4);
  const int bOff = 16384 + (wc << 12) + ((fr >> 1) << 7) + (slotF << 4);

  const int lg0 = (tid >> 3), lg1 = 64 + (tid >> 3);
  const int su0 = (tid & 7) ^ (lg0 & 7), su1 = (tid & 7) ^ (lg1 & 7);
  const int rowp0 = lg0 * 2 + (su0 >> 2), rowp1 = lg1 * 2 + (su1 >> 2);
  const int kb0 = (su0 & 3) << 4, kb1 = (su1 & 3) << 4;
  const char* pA0 = (const char*)A  + (size_t)(row0 + rowp0) * (KW * 2) + kb0;
  const char* pA1 = (const char*)A  + (size_t)(row0 + rowp1) * (KW * 2) + kb1;
  const char* pB0 = (const char*)Bt + (size_t)(col0 + rowp0) * (KW * 2) + kb0;
  const char* pB1 = (const char*)Bt + (size_t)(col0 + rowp1) * (KW * 2) + kb1;

  auto stageTile = [&](int T) {   // 4 gld per wave
    char* dst = smem + (size_t)(T & 3) * 32768;
    const size_t ko = (size_t)T * 64;
    gld_lds16(pA0 + ko, dst + 0     + tid * 16);
    gld_lds16(pA1 + ko, dst + 8192  + tid * 16);
    gld_lds16(pB0 + ko, dst + 16384 + tid * 16);
    gld_lds16(pB1 + ko, dst + 24576 + tid * 16);
  };

  f32x4 acc[8][4] = {};
  bf16x8 bA[4], bB[4];

  stageTile(0); stageTile(1); stageTile(2);
  VMC(4);
  __builtin_amdgcn_s_barrier();
  {
    const char* bP = smem + bOff;
#pragma unroll
    for (int n = 0; n < 4; ++n) bA[n] = *(const bf16x8*)(bP + n * 1024);
  }
  SB0();

  auto doIter = [&](int T, bf16x8 (&bCur)[4], bf16x8 (&bNxt)[4]) {
    const char* aP = smem + (size_t)(T & 3) * 32768 + aOff;
    const char* bP = smem + (size_t)((T + 1) & 3) * 32768 + bOff;
    bf16x8 a[8];
#pragma unroll
    for (int m = 0; m < 4; ++m) a[m] = *(const bf16x8*)(aP + m * 1024);
    SB0();
#pragma unroll
    for (int m = 4; m < 8; ++m) a[m] = *(const bf16x8*)(aP + m * 1024);
    SB0();
#pragma unroll
    for (int n = 0; n < 4; ++n) bNxt[n] = *(const bf16x8*)(bP + n * 1024);
    SB0();
    if (T + 3 < NT) stageTile(T + 3);
    SB0();
    LGKM(8);
    SB0();
    __builtin_amdgcn_s_setprio(1);
#pragma unroll
    for (int m = 0; m < 4; ++m)
#pragma unroll
      for (int n = 0; n < 4; ++n)
        acc[m][n] = __builtin_amdgcn_mfma_f32_16x16x32_bf16(a[m], bCur[n], acc[m][n], 0, 0, 0);
    SB0();
    LGKM(4);
    SB0();
#pragma unroll
    for (int m = 4; m < 8; ++m)
#pragma unroll
      for (int n = 0; n < 4; ++n)
        acc[m][n] = __builtin_amdgcn_mfma_f32_16x16x32_bf16(a[m], bCur[n], acc[m][n], 0, 0, 0);
    __builtin_amdgcn_s_setprio(0);
    SB0();
    LGKM(0);
    if (T + 3 < NT) { VMC(4); }
    else            { VMC(0); }
    __builtin_amdgcn_s_barrier();
  };

  for (int t = 0; t < NT - 2; t += 2) {
    doIter(t,     bA, bB);
    doIter(t + 1, bB, bA);
  }
  doIter(NT - 2, bA, bB);

  {  // final tile NT-1 (uses bB)
    const char* aP = smem + (size_t)((NT - 1) & 3) * 32768 + aOff;
    bf16x8 a[8];
#pragma unroll
    for (int m = 0; m < 4; ++m) a[m] = *(const bf16x8*)(aP + m * 1024);
    SB0();
#pragma unroll
    for (int m = 4; m < 8; ++m) a[m] = *(const bf16x8*)(aP + m * 1024);
    SB0();
    LGKM(4);
    SB0();
    __builtin_amdgcn_s_setprio(1);
#pragma unroll
    for (int m = 0; m < 4; ++m)
#pragma unroll
      for (int n = 0; n < 4; ++n)
        acc[m][n] = __builtin_amdgcn_mfma_f32_16x16x32_bf16(a[m], bB[n], acc[m][n], 0, 0, 0);
    SB0();
    LGKM(0);
    SB0();
#pragma unroll
    for (int m = 4; m < 8; ++m)
#pragma unroll
      for (int n = 0; n < 4; ++n)
        acc[m][n] = __builtin_amdgcn_mfma_f32_16x16x32_bf16(a[m], bB[n], acc[m][n], 0, 0, 0);
    __builtin_amdgcn_s_setprio(0);
  }

  // epilogue: h = relu(acc + hS2[b,c] + hVT[c, fq*4+j])
#pragma unroll
  for (int n = 0; n < 4; ++n) {
    const int c = col0 + wc * 64 + n * 16 + fr;
    const f32x4 hv = *(const f32x4*)&hVT[(size_t)c * 16 + fq * 4];
#pragma unroll
    for (int m = 0; m < 8; ++m) {
      const int rbase = row0 + wr * 128 + m * 16;
      const float hs = hS2[(size_t)(rbase >> 4) * N1 + c];
#pragma unroll
      for (int j = 0; j < 4; ++j) {
        const int r = rbase + fq * 4 + j;
        float v = acc[m][n][j] + hs + hv[j];
        outH[(size_t)r * N1 + c] = __float2bfloat16(v > 0.f ? v : 0.f);
      }
    }
  }
}

// ---------------------------------------------------------------------------
// gemm128_pipe: 128x128 tile, BK=32, 4 waves (2x2), 4-deep LDS ring, counted
// pipeline (R7-proven). Template NT (K = NT*32).
// EPI 0 (GEMM2): out1 = eta_M^T scatter (acc+bias); fused eta contraction ->
//   out0[b,c] = phi[b,c] - sum_m rho*(acc+bias) via FMA + shfl_xor(16/32).
// EPI 1 (GEMM_S split-K): blockIdx.z selects K-slice of 512 + partial buffer.
template <int EPI, int NT>
__global__ void __launch_bounds__(256, 2)
gemm128_pipe_kernel(const bf16* __restrict__ A, int lda,
                    const bf16* __restrict__ Bt, int ldb,
                    const float* __restrict__ bias0, const float* __restrict__ rho,
                    const float* __restrict__ phi,
                    float* __restrict__ outS, float* __restrict__ out0) {
  extern __shared__ __align__(16) char smem[];

  if (EPI == 1) {
    const int z = blockIdx.z;
    A    += (size_t)z * 512;
    Bt   += (size_t)z * 512;
    outS += (size_t)z * ((size_t)B_ * N1);
  }

  const int tid  = threadIdx.x;
  const int lane = tid & 63;
  const int wave = tid >> 6;                 // 0..3
  const int wr = wave >> 1, wc = wave & 1;   // 2x2 wave grid
  const int fr = lane & 15, fq = lane >> 4;
  const int row0 = blockIdx.y * 128, col0 = blockIdx.x * 128;

  const int slotF = (((fr & 1) << 2) | fq) ^ ((fr >> 1) & 7);
  const int aOff = (wr << 12) + ((fr >> 1) << 7) + (slotF << 4);
  const int bOff = 8192 + (wc << 12) + ((fr >> 1) << 7) + (slotF << 4);

  const int lgl = tid >> 3;
  const int su  = (tid & 7) ^ (lgl & 7);
  const int rp0 = lgl * 2 + (su >> 2);
  const int rp1 = (32 + lgl) * 2 + (su >> 2);
  const int kb  = (su & 3) << 4;
  const char* pA0 = (const char*)A  + (size_t)(row0 + rp0) * ((size_t)lda * 2) + kb;
  const char* pA1 = (const char*)A  + (size_t)(row0 + rp1) * ((size_t)lda * 2) + kb;
  const char* pB0 = (const char*)Bt + (size_t)(col0 + rp0) * ((size_t)ldb * 2) + kb;
  const char* pB1 = (const char*)Bt + (size_t)(col0 + rp1) * ((size_t)ldb * 2) + kb;

  auto stageTile = [&](int T) {   // 4 gld per wave
    char* dst = smem + (size_t)(T & 3) * 16384;
    const size_t ko = (size_t)T * 64;
    gld_lds16(pA0 + ko, dst + 0     + tid * 16);
    gld_lds16(pA1 + ko, dst + 4096  + tid * 16);
    gld_lds16(pB0 + ko, dst + 8192  + tid * 16);
    gld_lds16(pB1 + ko, dst + 12288 + tid * 16);
  };

  f32x4 acc[4][4] = {};
  bf16x8 bA[4], bB[4];

  stageTile(0); stageTile(1); stageTile(2);
  VMC(4);
  __builtin_amdgcn_s_barrier();
  {
    const char* bP = smem + bOff;
#pragma unroll
    for (int n = 0; n < 4; ++n) bA[n] = *(const bf16x8*)(bP + n * 1024);
  }
  SB0();

  auto doIter = [&](int T, bf16x8 (&bCur)[4], bf16x8 (&bNxt)[4]) {
    const char* aP = smem + (size_t)(T & 3) * 16384 + aOff;
    const char* bP = smem + (size_t)((T + 1) & 3) * 16384 + bOff;
    bf16x8 a[4];
#pragma unroll
    for (int m = 0; m < 4; ++m) a[m] = *(const bf16x8*)(aP + m * 1024);
    SB0();
#pragma unroll
    for (int n = 0; n < 4; ++n) bNxt[n] = *(const bf16x8*)(bP + n * 1024);
    SB0();
    if (T + 3 < NT) stageTile(T + 3);
    SB0();
    LGKM(4);                     // a[0..3] landed; bNxt may still fly
    SB0();
    __builtin_amdgcn_s_setprio(1);
#pragma unroll
    for (int m = 0; m < 4; ++m)
#pragma unroll
      for (int n = 0; n < 4; ++n)
        acc[m][n] = __builtin_amdgcn_mfma_f32_16x16x32_bf16(a[m], bCur[n], acc[m][n], 0, 0, 0);
    __builtin_amdgcn_s_setprio(0);
    SB0();
    LGKM(0);
    if (T + 3 < NT) { VMC(4); }
    else            { VMC(0); }
    __builtin_amdgcn_s_barrier();
  };

  for (int t = 0; t < NT - 2; t += 2) {
    doIter(t,     bA, bB);
    doIter(t + 1, bB, bA);
  }
  doIter(NT - 2, bA, bB);

  {  // final tile NT-1 (uses bB)
    const char* aP = smem + (size_t)((NT - 1) & 3) * 16384 + aOff;
    bf16x8 a[4];
#pragma unroll
    for (int m = 0; m < 4; ++m) a[m] = *(const bf16x8*)(aP + m * 1024);
    SB0();
    LGKM(0);
    SB0();
    __builtin_amdgcn_s_setprio(1);
#pragma unroll
    for (int m = 0; m < 4; ++m)
#pragma unroll
      for (int n = 0; n < 4; ++n)
        acc[m][n] = __builtin_amdgcn_mfma_f32_16x16x32_bf16(a[m], bB[n], acc[m][n], 0, 0, 0);
    __builtin_amdgcn_s_setprio(0);
  }

  if (EPI == 0) {
#pragma unroll
    for (int m = 0; m < 4; ++m) {
      const int bg = (row0 >> 4) + wr * 4 + m;                 // batch index
      const f32x4 rv = *(const f32x4*)&rho[bg * 16 + fq * 4];
#pragma unroll
      for (int n = 0; n < 4; ++n) {
        const int c = col0 + wc * 64 + n * 16 + fr;
        const float bias = bias0[c];
        float part = 0.f;
#pragma unroll
        for (int j = 0; j < 4; ++j) {
          float v = acc[m][n][j] + bias;
          outS[(size_t)bg * (LS_ * M_) + (size_t)c * M_ + (fq * 4 + j)] = v;
          part += rv[j] * v;
        }
        part += __shfl_xor(part, 16);
        part += __shfl_xor(part, 32);
        if (fq == 0)
          out0[(size_t)bg * LS_ + c] = phi[(size_t)bg * LS_ + c] - part;
      }
    }
  } else {
#pragma unroll
    for (int m = 0; m < 4; ++m) {
#pragma unroll
      for (int n = 0; n < 4; ++n) {
        const int c = col0 + wc * 64 + n * 16 + fr;
#pragma unroll
        for (int j = 0; j < 4; ++j) {
          const int r = row0 + wr * 64 + m * 16 + fq * 4 + j;
          outS[(size_t)r * N1 + c] = acc[m][n][j];
        }
      }
    }
  }
}

// ---------------------------------------------------------------------------
__global__ void rho_kernel(const bf16* __restrict__ h, const float* __restrict__ w2r,
                           const float* __restrict__ b2r, float* __restrict__ rho) {
  int r = blockIdx.x;
  int t = threadIdx.x;
  int lane = t & 63, wave = t >> 6;
  const bf16* hr = h + (size_t)r * N1 + H_;
  float s = 0.f;
#pragma unroll
  for (int j = 0; j < 8; ++j)
    s += __bfloat162float(hr[t * 8 + j]) * w2r[t * 8 + j];
#pragma unroll
  for (int off = 32; off > 0; off >>= 1) s += __shfl_down(s, off);
  __shared__ float ws4[4];
  if (lane == 0) ws4[wave] = s;
  __syncthreads();
  if (t == 0) rho[r] = ws4[0] + ws4[1] + ws4[2] + ws4[3] + b2r[0];
}

// ---------------------------------------------------------------------------
extern "C" void kernel_launch(void* const* d_in, const int* in_sizes, int n_in,
                              void* d_out, int out_size, void* d_ws, size_t ws_size,
                              hipStream_t stream) {
  const float* phi = (const float*)d_in[0];
  const float* wMr = (const float*)d_in[1];
  const float* wMi = (const float*)d_in[2];
  const float* vM  = (const float*)d_in[3];
  const float* W1e = (const float*)d_in[4];
  const float* b1e = (const float*)d_in[5];
  const float* W2e = (const float*)d_in[6];
  const float* b2e = (const float*)d_in[7];
  const float* W1r = (const float*)d_in[8];
  const float* b1r = (const float*)d_in[9];
  const float* W2r = (const float*)d_in[10];
  const float* b2r = (const float*)d_in[11];

  float* out0 = (float*)d_out;            // phi_optimal [B, LS]
  float* out1 = out0 + (size_t)B_ * LS_;  // eta_M^T     [B, LS, M]

  bf16* Awr   = (bf16*)d_ws;                         // [4096, 2048]
  bf16* W1sT  = Awr  + (size_t)ROWS * KW;            // [4096, 2048]
  bf16* W1wT  = W1sT + (size_t)N1 * KW;              // [4096, 2048]
  bf16* h     = W1wT + (size_t)N1 * KW;              // [4096, 4096]
  bf16* W2t   = h + (size_t)ROWS * N1;               // [1024, 2048]
  bf16* sfeat = W2t + (size_t)LS_ * H_;              // [256, 2048]
  float* hSp  = (float*)(sfeat + (size_t)B_ * 2048); // 4 x [256, 4096] partials
  float* hS2  = hSp + (size_t)4 * B_ * N1;           // [256, 4096] summed + bias
  float* hVT  = hS2 + (size_t)B_ * N1;               // [4096, 16]
  float* rho  = hVT + (size_t)N1 * 16;               // [4096]

  (void)hipFuncSetAttribute(reinterpret_cast<const void*>(gemm1_256_kernel),
                            hipFuncAttributeMaxDynamicSharedMemorySize, 131072);
  (void)hipFuncSetAttribute(reinterpret_cast<const void*>(gemm128_pipe_kernel<0, 64>),
                            hipFuncAttributeMaxDynamicSharedMemorySize, 65536);
  (void)hipFuncSetAttribute(reinterpret_cast<const void*>(gemm128_pipe_kernel<1, 16>),
                            hipFuncAttributeMaxDynamicSharedMemorySize, 65536);

  // merged preprocessing: hv | 4x W1-transpose | W2-transpose | awr | sfeat
  prep_kernel<<<9984, 256, 0, stream>>>(phi, wMr, wMi, vM, W1e, W1r, W2e,
                                        sfeat, Awr, W1sT, W1wT, W2t, hVT);

  // GEMM_S split-K x4: hSp[z] = sfeat @ W1sT[:, z*512:(z+1)*512]^T
  gemm128_pipe_kernel<1, 16><<<dim3(N1 / 128, B_ / 128, 4), 256, 65536, stream>>>(
      sfeat, 2048, W1sT, KW, nullptr, nullptr, nullptr, hSp, nullptr);

  // hS2 = sum4(hSp) + bias
  hsum_kernel<<<(B_ * N1 / 4) / 256, 256, 0, stream>>>(hSp, b1e, b1r, hS2);

  // GEMM_W + fused epilogue: h = relu(Awr@W1wT^T + hS2 + hVT)
  gemm1_256_kernel<<<dim3(N1 / 256, ROWS / 256), 512, 131072, stream>>>(
      Awr, W1wT, hS2, hVT, h);

  // rho before GEMM2 (depends only on h)
  rho_kernel<<<ROWS, 256, 0, stream>>>(h, W2r, b2r, rho);

  // GEMM2: out1 scatter + fused eta contraction + out0 = phi - eta
  gemm128_pipe_kernel<0, 64><<<dim3(LS_ / 128, ROWS / 128), 256, 65536, stream>>>(
      h, N1, W2t, H_, b2e, rho, phi, out1, out0);
}

// Round 10
// 142.027 us; speedup vs baseline: 2.5939x; 1.0471x over previous
//
#include <hip/hip_runtime.h>
#include <hip/hip_bf16.h>
#include <stdint.h>

// Problem constants
#define B_    256
#define LS_   1024
#define LW_   1024
#define LV_   1024
#define M_    16
#define D_    5120
#define H_    2048
#define ROWS  4096   // B*M
#define N1    4096   // H (eta) + H (rho) fused
#define KW    2048   // K of the per-row (wr|wi) GEMM

typedef __hip_bfloat16 bf16;
typedef __bf16 bf16x8 __attribute__((ext_vector_type(8)));
typedef __bf16 bf16x4 __attribute__((ext_vector_type(4)));
typedef float f32x4 __attribute__((ext_vector_type(4)));

#define SB0() __builtin_amdgcn_sched_barrier(0)
#define LGKM(n) asm volatile("s_waitcnt lgkmcnt(" #n ")" ::: "memory")
#define VMC(n)  asm volatile("s_waitcnt vmcnt(" #n ")" ::: "memory")

// ---------------------------------------------------------------------------
// async global->LDS, 16B per lane (HW: wave-uniform LDS base + lane*16).
__device__ __forceinline__ void gld_lds16(const void* g, void* l) {
  auto gp = (const __attribute__((address_space(1))) uint32_t*)(uintptr_t)g;
  auto lp = (__attribute__((address_space(3))) uint32_t*)(uint32_t)(uintptr_t)l;
  __builtin_amdgcn_global_load_lds(gp, lp, 16, 0, 0);
}

// ---------------------------------------------------------------------------
// Merged preprocessing kernel: one launch, block-range dispatch.
//   [0,256)     hv    | [256,4352) tw1 | [4352,4864) tw2 | [4864,8960) awr |
//   [8960,9984) sfeat
__device__ __forceinline__ void transpose64_body(char* sm, const float* __restrict__ in,
                                                 bf16* __restrict__ out,
                                                 int C, int R, int r0, int c0, int t) {
  float (*tile)[65] = (float (*)[65])sm;
  const int tx = t & 15, ty = t >> 4;   // 16 x 16
#pragma unroll
  for (int i = 0; i < 4; ++i) {
    const float4 v = *(const float4*)&in[(size_t)(r0 + ty + i * 16) * C + c0 + tx * 4];
    tile[ty + i * 16][tx * 4 + 0] = v.x;
    tile[ty + i * 16][tx * 4 + 1] = v.y;
    tile[ty + i * 16][tx * 4 + 2] = v.z;
    tile[ty + i * 16][tx * 4 + 3] = v.w;
  }
  __syncthreads();
#pragma unroll
  for (int i = 0; i < 4; ++i) {
    const int n = c0 + ty + i * 16;
    bf16x4 o;
#pragma unroll
    for (int j = 0; j < 4; ++j) o[j] = (__bf16)tile[tx * 4 + j][ty + i * 16];
    *(bf16x4*)&out[(size_t)n * R + r0 + tx * 4] = o;
  }
}

__global__ void __launch_bounds__(256)
prep_kernel(const float* __restrict__ phi,
            const float* __restrict__ wMr, const float* __restrict__ wMi,
            const float* __restrict__ vM,
            const float* __restrict__ W1e, const float* __restrict__ W1r,
            const float* __restrict__ W2e,
            bf16* __restrict__ sfeat, bf16* __restrict__ Awr,
            bf16* __restrict__ W1sT, bf16* __restrict__ W1wT,
            bf16* __restrict__ W2t, float* __restrict__ hVT) {
  __shared__ __align__(16) char sm[32768];
  const int bid = blockIdx.x;
  const int t = threadIdx.x;

  if (bid < 256) {
    // ---- hv ----
    float (*vs)[16] = (float (*)[16])sm;
    float (*ws)[16] = (float (*)[16])(sm + 16384);
    const float* Wb = (bid < 128) ? W1e : W1r;
    const int nbase = (bid & 127) * 16;
    const int nout = ((bid < 128) ? 0 : 2048) + nbase;
    const int m = t & 15, nl = t >> 4;
    float acc = 0.f;
    for (int l0 = 0; l0 < 1024; l0 += 256) {
      __syncthreads();
#pragma unroll
      for (int i = 0; i < 16; ++i) {
        int e = i * 256 + t, l = e >> 4, n = e & 15;
        vs[l][n] = vM[(size_t)(l0 + l) * 16 + n];
        ws[l][n] = Wb[(size_t)(4096 + l0 + l) * 2048 + nbase + n];
      }
      __syncthreads();
#pragma unroll 8
      for (int ll = 0; ll < 256; ++ll)
        acc += vs[ll][m] * ws[ll][nl];
    }
    hVT[(size_t)(nout + nl) * 16 + m] = acc;
  } else if (bid < 4352) {
    // ---- tw1: four 2048x2048 transposes ----
    const int idx = bid - 256;
    const int z = idx >> 10, rem = idx & 1023;
    const float* src = (z == 0 || z == 2) ? W1e : W1r;
    src += (z < 2) ? 0 : (size_t)2048 * 2048;
    bf16* dst = (z < 2) ? W1sT : W1wT;
    dst += (z == 0 || z == 2) ? 0 : (size_t)2048 * 2048;
    transpose64_body(sm, src, dst, 2048, 2048, (rem >> 5) * 64, (rem & 31) * 64, t);
  } else if (bid < 4864) {
    // ---- tw2: W2e [2048,1024] -> W2t ----
    const int idx = bid - 4352;
    transpose64_body(sm, W2e, W2t, LS_, H_, (idx >> 4) * 64, (idx & 15) * 64, t);
  } else if (bid < 8960) {
    // ---- awr ----
    const int idx = bid - 4864;
    const int b = idx >> 4, l0 = (idx & 15) * 64;
    float (*tr)[17] = (float (*)[17])sm;
    float (*ti)[17] = (float (*)[17])(sm + 4352 * 4);
    const float* wrb = wMr + (size_t)b * (LW_ * M_) + (size_t)l0 * 16;
    const float* wib = wMi + (size_t)b * (LW_ * M_) + (size_t)l0 * 16;
#pragma unroll
    for (int i = 0; i < 4; ++i) {
      int e = i * 256 + t, l = e >> 4, m = e & 15;
      tr[l][m] = wrb[e];
      ti[l][m] = wib[e];
    }
    __syncthreads();
    int m = t >> 4, t4 = t & 15;
    bf16* outR = Awr + (size_t)(b * 16 + m) * KW + l0;
#pragma unroll
    for (int j = 0; j < 4; ++j) outR[t4 * 4 + j]        = __float2bfloat16(tr[t4 * 4 + j][m]);
#pragma unroll
    for (int j = 0; j < 4; ++j) outR[1024 + t4 * 4 + j] = __float2bfloat16(ti[t4 * 4 + j][m]);
  } else {
    // ---- sfeat ----
    const int i = (bid - 8960) * 256 + t;
    const int b = i >> 10, l = i & 1023;
    float p = phi[i];
    float s, c;
    sincosf(p, &s, &c);
    sfeat[b * 2048 + l]        = __float2bfloat16(0.03125f * c);
    sfeat[b * 2048 + 1024 + l] = __float2bfloat16(0.03125f * s);
  }
}

// ---------------------------------------------------------------------------
// hS2[b,c] = sum_z hSp[z][b,c] + bias[c]   (bias = b1e | b1r split at H_)
__global__ void __launch_bounds__(256)
hsum_kernel(const float* __restrict__ hSp, const float* __restrict__ b1e,
            const float* __restrict__ b1r, float* __restrict__ hS2) {
  const int i = (blockIdx.x * 256 + threadIdx.x) * 4;
  const int c = i & (N1 - 1);
  f32x4 v = *(const f32x4*)&hSp[i];
  v = v + *(const f32x4*)&hSp[(size_t)B_ * N1 + i];
  v = v + *(const f32x4*)&hSp[(size_t)2 * B_ * N1 + i];
  v = v + *(const f32x4*)&hSp[(size_t)3 * B_ * N1 + i];
  const float* bp = (c < H_) ? &b1e[c] : &b1r[c - H_];
  v = v + *(const f32x4*)bp;
  *(f32x4*)&hS2[i] = v;
}

// ---------------------------------------------------------------------------
// GEMM_W: 256x256 tile, BK=32, 8 waves, 4-deep LDS ring, counted lgkmcnt
// pipeline (R4-proven). Epilogue:
//   col0 <  H_: h = relu(acc + hS2 + hVT) -> bf16 store (eta half)
//   col0 >= H_: rho partials rhoP[r][col0/256-8] = sum_c relu(v)*W2r[c-H_]
//               (h never stored -- rho is its only consumer)
__global__ void __launch_bounds__(512, 2)
gemm1_256_kernel(const bf16* __restrict__ A, const bf16* __restrict__ Bt,
                 const float* __restrict__ hS2, const float* __restrict__ hVT,
                 const float* __restrict__ w2r,
                 bf16* __restrict__ outH, float* __restrict__ rhoP) {
  extern __shared__ __align__(16) char smem[];
  constexpr int NT = KW / 32;   // 64 K-tiles

  const int tid  = threadIdx.x;
  const int lane = tid & 63;
  const int wave = tid >> 6;
  const int wr = wave >> 2, wc = wave & 3;   // 2 x 4 wave grid, wave-tile 128x64
  const int fr = lane & 15, fq = lane >> 4;
  const int row0 = blockIdx.y * 256, col0 = blockIdx.x * 256;

  const int slotF = (((fr & 1) << 2) | fq) ^ ((fr >> 1) & 7);
  const int aOff = (wr << 13) + ((fr >> 1) << 7) + (slotF << 4);
  const int bOff = 16384 + (wc << 12) + ((fr >> 1) << 7) + (slotF << 4);

  const int lg0 = (tid >> 3), lg1 = 64 + (tid >> 3);
  const int su0 = (tid & 7) ^ (lg0 & 7), su1 = (tid & 7) ^ (lg1 & 7);
  const int rowp0 = lg0 * 2 + (su0 >> 2), rowp1 = lg1 * 2 + (su1 >> 2);
  const int kb0 = (su0 & 3) << 4, kb1 = (su1 & 3) << 4;
  const char* pA0 = (const char*)A  + (size_t)(row0 + rowp0) * (KW * 2) + kb0;
  const char* pA1 = (const char*)A  + (size_t)(row0 + rowp1) * (KW * 2) + kb1;
  const char* pB0 = (const char*)Bt + (size_t)(col0 + rowp0) * (KW * 2) + kb0;
  const char* pB1 = (const char*)Bt + (size_t)(col0 + rowp1) * (KW * 2) + kb1;

  auto stageTile = [&](int T) {   // 4 gld per wave
    char* dst = smem + (size_t)(T & 3) * 32768;
    const size_t ko = (size_t)T * 64;
    gld_lds16(pA0 + ko, dst + 0     + tid * 16);
    gld_lds16(pA1 + ko, dst + 8192  + tid * 16);
    gld_lds16(pB0 + ko, dst + 16384 + tid * 16);
    gld_lds16(pB1 + ko, dst + 24576 + tid * 16);
  };

  f32x4 acc[8][4] = {};
  bf16x8 bA[4], bB[4];

  stageTile(0); stageTile(1); stageTile(2);
  VMC(4);
  __builtin_amdgcn_s_barrier();
  {
    const char* bP = smem + bOff;
#pragma unroll
    for (int n = 0; n < 4; ++n) bA[n] = *(const bf16x8*)(bP + n * 1024);
  }
  SB0();

  auto doIter = [&](int T, bf16x8 (&bCur)[4], bf16x8 (&bNxt)[4]) {
    const char* aP = smem + (size_t)(T & 3) * 32768 + aOff;
    const char* bP = smem + (size_t)((T + 1) & 3) * 32768 + bOff;
    bf16x8 a[8];
#pragma unroll
    for (int m = 0; m < 4; ++m) a[m] = *(const bf16x8*)(aP + m * 1024);
    SB0();
#pragma unroll
    for (int m = 4; m < 8; ++m) a[m] = *(const bf16x8*)(aP + m * 1024);
    SB0();
#pragma unroll
    for (int n = 0; n < 4; ++n) bNxt[n] = *(const bf16x8*)(bP + n * 1024);
    SB0();
    if (T + 3 < NT) stageTile(T + 3);
    SB0();
    LGKM(8);
    SB0();
    __builtin_amdgcn_s_setprio(1);
#pragma unroll
    for (int m = 0; m < 4; ++m)
#pragma unroll
      for (int n = 0; n < 4; ++n)
        acc[m][n] = __builtin_amdgcn_mfma_f32_16x16x32_bf16(a[m], bCur[n], acc[m][n], 0, 0, 0);
    SB0();
    LGKM(4);
    SB0();
#pragma unroll
    for (int m = 4; m < 8; ++m)
#pragma unroll
      for (int n = 0; n < 4; ++n)
        acc[m][n] = __builtin_amdgcn_mfma_f32_16x16x32_bf16(a[m], bCur[n], acc[m][n], 0, 0, 0);
    __builtin_amdgcn_s_setprio(0);
    SB0();
    LGKM(0);
    if (T + 3 < NT) { VMC(4); }
    else            { VMC(0); }
    __builtin_amdgcn_s_barrier();
  };

  for (int t = 0; t < NT - 2; t += 2) {
    doIter(t,     bA, bB);
    doIter(t + 1, bB, bA);
  }
  doIter(NT - 2, bA, bB);

  {  // final tile NT-1 (uses bB)
    const char* aP = smem + (size_t)((NT - 1) & 3) * 32768 + aOff;
    bf16x8 a[8];
#pragma unroll
    for (int m = 0; m < 4; ++m) a[m] = *(const bf16x8*)(aP + m * 1024);
    SB0();
#pragma unroll
    for (int m = 4; m < 8; ++m) a[m] = *(const bf16x8*)(aP + m * 1024);
    SB0();
    LGKM(4);
    SB0();
    __builtin_amdgcn_s_setprio(1);
#pragma unroll
    for (int m = 0; m < 4; ++m)
#pragma unroll
      for (int n = 0; n < 4; ++n)
        acc[m][n] = __builtin_amdgcn_mfma_f32_16x16x32_bf16(a[m], bB[n], acc[m][n], 0, 0, 0);
    SB0();
    LGKM(0);
    SB0();
#pragma unroll
    for (int m = 4; m < 8; ++m)
#pragma unroll
      for (int n = 0; n < 4; ++n)
        acc[m][n] = __builtin_amdgcn_mfma_f32_16x16x32_bf16(a[m], bB[n], acc[m][n], 0, 0, 0);
    __builtin_amdgcn_s_setprio(0);
  }

  if (col0 < H_) {
    // eta half: h = relu(acc + hS2 + hVT)
#pragma unroll
    for (int n = 0; n < 4; ++n) {
      const int c = col0 + wc * 64 + n * 16 + fr;
      const f32x4 hv = *(const f32x4*)&hVT[(size_t)c * 16 + fq * 4];
#pragma unroll
      for (int m = 0; m < 8; ++m) {
        const int rbase = row0 + wr * 128 + m * 16;
        const float hs = hS2[(size_t)(rbase >> 4) * N1 + c];
#pragma unroll
        for (int j = 0; j < 4; ++j) {
          const int r = rbase + fq * 4 + j;
          float v = acc[m][n][j] + hs + hv[j];
          outH[(size_t)r * N1 + c] = __float2bfloat16(v > 0.f ? v : 0.f);
        }
      }
    }
  } else {
    // rho half: partial dot with W2r; no h store
    const int cb = (col0 >> 8) - 8;   // 0..7
    float* rhoT = (float*)smem;       // [2 wr][4 wc][128] f32 = 4KB, ring is dead
    f32x4 hv4[4];
    float w2[4];
#pragma unroll
    for (int n = 0; n < 4; ++n) {
      const int c = col0 + wc * 64 + n * 16 + fr;
      hv4[n] = *(const f32x4*)&hVT[(size_t)c * 16 + fq * 4];
      w2[n] = w2r[c - H_];
    }
#pragma unroll
    for (int m = 0; m < 8; ++m) {
      const int rbase = row0 + wr * 128 + m * 16;
      const float* hrow = &hS2[(size_t)(rbase >> 4) * N1];
      f32x4 rsv = {0.f, 0.f, 0.f, 0.f};
#pragma unroll
      for (int n = 0; n < 4; ++n) {
        const int c = col0 + wc * 64 + n * 16 + fr;
        const float hs = hrow[c];
#pragma unroll
        for (int j = 0; j < 4; ++j) {
          float v = acc[m][n][j] + hs + hv4[n][j];
          v = v > 0.f ? v : 0.f;
          rsv[j] += v * w2[n];
        }
      }
#pragma unroll
      for (int j = 0; j < 4; ++j) {
        rsv[j] += __shfl_xor(rsv[j], 1);
        rsv[j] += __shfl_xor(rsv[j], 2);
        rsv[j] += __shfl_xor(rsv[j], 4);
        rsv[j] += __shfl_xor(rsv[j], 8);
      }
      if (fr == 0)
        *(f32x4*)&rhoT[((wr * 4 + wc) << 7) + m * 16 + fq * 4] = rsv;
    }
    __syncthreads();
    if (tid < 256) {
      const int wrr = tid >> 7, lr = tid & 127;
      const float* rt = &rhoT[(wrr * 4) << 7];
      const float s = rt[lr] + rt[128 + lr] + rt[256 + lr] + rt[384 + lr];
      rhoP[(size_t)(row0 + wrr * 128 + lr) * 8 + cb] = s;
    }
  }
}

// ---------------------------------------------------------------------------
// gemm128_pipe: 128x128 tile, BK=32, 4 waves (2x2), 4-deep LDS ring, counted
// pipeline (R7-proven). Template NT (K = NT*32).
// EPI 0 (GEMM2): prologue reduces rhoP[128][8]+b2r -> rhoL (LDS); out1 =
//   eta_M^T scatter (acc+bias); out0 = phi - sum_m rhoL*(acc+bias).
// EPI 1 (GEMM_S split-K): blockIdx.z selects K-slice of 512 + partial buffer.
template <int EPI, int NT>
__global__ void __launch_bounds__(256, 2)
gemm128_pipe_kernel(const bf16* __restrict__ A, int lda,
                    const bf16* __restrict__ Bt, int ldb,
                    const float* __restrict__ bias0,
                    const float* __restrict__ rhoP, const float* __restrict__ b2r,
                    const float* __restrict__ phi,
                    float* __restrict__ outS, float* __restrict__ out0) {
  extern __shared__ __align__(16) char smem[];

  if (EPI == 1) {
    const int z = blockIdx.z;
    A    += (size_t)z * 512;
    Bt   += (size_t)z * 512;
    outS += (size_t)z * ((size_t)B_ * N1);
  }

  const int tid  = threadIdx.x;
  const int lane = tid & 63;
  const int wave = tid >> 6;                 // 0..3
  const int wr = wave >> 1, wc = wave & 1;   // 2x2 wave grid
  const int fr = lane & 15, fq = lane >> 4;
  const int row0 = blockIdx.y * 128, col0 = blockIdx.x * 128;

  // rho prologue (EPI 0): reduce partials into LDS before staging so the
  // loads are consumed (vmcnt drained) ahead of the counted-vmcnt pipeline.
  if (EPI == 0) {
    if (tid < 128) {
      const float* pp = &rhoP[(size_t)(row0 + tid) * 8];
      const f32x4 p0 = *(const f32x4*)pp;
      const f32x4 p1 = *(const f32x4*)(pp + 4);
      const float s = p0[0] + p0[1] + p0[2] + p0[3] +
                      p1[0] + p1[1] + p1[2] + p1[3] + b2r[0];
      ((float*)(smem + 65536))[tid] = s;
    }
    LGKM(0);
    SB0();
  }

  const int slotF = (((fr & 1) << 2) | fq) ^ ((fr >> 1) & 7);
  const int aOff = (wr << 12) + ((fr >> 1) << 7) + (slotF << 4);
  const int bOff = 8192 + (wc << 12) + ((fr >> 1) << 7) + (slotF << 4);

  const int lgl = tid >> 3;
  const int su  = (tid & 7) ^ (lgl & 7);
  const int rp0 = lgl * 2 + (su >> 2);
  const int rp1 = (32 + lgl) * 2 + (su >> 2);
  const int kb  = (su & 3) << 4;
  const char* pA0 = (const char*)A  + (size_t)(row0 + rp0) * ((size_t)lda * 2) + kb;
  const char* pA1 = (const char*)A  + (size_t)(row0 + rp1) * ((size_t)lda * 2) + kb;
  const char* pB0 = (const char*)Bt + (size_t)(col0 + rp0) * ((size_t)ldb * 2) + kb;
  const char* pB1 = (const char*)Bt + (size_t)(col0 + rp1) * ((size_t)ldb * 2) + kb;

  auto stageTile = [&](int T) {   // 4 gld per wave
    char* dst = smem + (size_t)(T & 3) * 16384;
    const size_t ko = (size_t)T * 64;
    gld_lds16(pA0 + ko, dst + 0     + tid * 16);
    gld_lds16(pA1 + ko, dst + 4096  + tid * 16);
    gld_lds16(pB0 + ko, dst + 8192  + tid * 16);
    gld_lds16(pB1 + ko, dst + 12288 + tid * 16);
  };

  f32x4 acc[4][4] = {};
  bf16x8 bA[4], bB[4];

  stageTile(0); stageTile(1); stageTile(2);
  VMC(4);
  __builtin_amdgcn_s_barrier();
  {
    const char* bP = smem + bOff;
#pragma unroll
    for (int n = 0; n < 4; ++n) bA[n] = *(const bf16x8*)(bP + n * 1024);
  }
  SB0();

  auto doIter = [&](int T, bf16x8 (&bCur)[4], bf16x8 (&bNxt)[4]) {
    const char* aP = smem + (size_t)(T & 3) * 16384 + aOff;
    const char* bP = smem + (size_t)((T + 1) & 3) * 16384 + bOff;
    bf16x8 a[4];
#pragma unroll
    for (int m = 0; m < 4; ++m) a[m] = *(const bf16x8*)(aP + m * 1024);
    SB0();
#pragma unroll
    for (int n = 0; n < 4; ++n) bNxt[n] = *(const bf16x8*)(bP + n * 1024);
    SB0();
    if (T + 3 < NT) stageTile(T + 3);
    SB0();
    LGKM(4);                     // a[0..3] landed; bNxt may still fly
    SB0();
    __builtin_amdgcn_s_setprio(1);
#pragma unroll
    for (int m = 0; m < 4; ++m)
#pragma unroll
      for (int n = 0; n < 4; ++n)
        acc[m][n] = __builtin_amdgcn_mfma_f32_16x16x32_bf16(a[m], bCur[n], acc[m][n], 0, 0, 0);
    __builtin_amdgcn_s_setprio(0);
    SB0();
    LGKM(0);
    if (T + 3 < NT) { VMC(4); }
    else            { VMC(0); }
    __builtin_amdgcn_s_barrier();
  };

  for (int t = 0; t < NT - 2; t += 2) {
    doIter(t,     bA, bB);
    doIter(t + 1, bB, bA);
  }
  doIter(NT - 2, bA, bB);

  {  // final tile NT-1 (uses bB)
    const char* aP = smem + (size_t)((NT - 1) & 3) * 16384 + aOff;
    bf16x8 a[4];
#pragma unroll
    for (int m = 0; m < 4; ++m) a[m] = *(const bf16x8*)(aP + m * 1024);
    SB0();
    LGKM(0);
    SB0();
    __builtin_amdgcn_s_setprio(1);
#pragma unroll
    for (int m = 0; m < 4; ++m)
#pragma unroll
      for (int n = 0; n < 4; ++n)
        acc[m][n] = __builtin_amdgcn_mfma_f32_16x16x32_bf16(a[m], bB[n], acc[m][n], 0, 0, 0);
    __builtin_amdgcn_s_setprio(0);
  }

  if (EPI == 0) {
    const float* rhoL = (const float*)(smem + 65536);
#pragma unroll
    for (int m = 0; m < 4; ++m) {
      const int bg = (row0 >> 4) + wr * 4 + m;                 // batch index
      const f32x4 rv = *(const f32x4*)&rhoL[wr * 64 + m * 16 + fq * 4];
#pragma unroll
      for (int n = 0; n < 4; ++n) {
        const int c = col0 + wc * 64 + n * 16 + fr;
        const float bias = bias0[c];
        float part = 0.f;
#pragma unroll
        for (int j = 0; j < 4; ++j) {
          float v = acc[m][n][j] + bias;
          outS[(size_t)bg * (LS_ * M_) + (size_t)c * M_ + (fq * 4 + j)] = v;
          part += rv[j] * v;
        }
        part += __shfl_xor(part, 16);
        part += __shfl_xor(part, 32);
        if (fq == 0)
          out0[(size_t)bg * LS_ + c] = phi[(size_t)bg * LS_ + c] - part;
      }
    }
  } else {
#pragma unroll
    for (int m = 0; m < 4; ++m) {
#pragma unroll
      for (int n = 0; n < 4; ++n) {
        const int c = col0 + wc * 64 + n * 16 + fr;
#pragma unroll
        for (int j = 0; j < 4; ++j) {
          const int r = row0 + wr * 64 + m * 16 + fq * 4 + j;
          outS[(size_t)r * N1 + c] = acc[m][n][j];
        }
      }
    }
  }
}

// ---------------------------------------------------------------------------
extern "C" void kernel_launch(void* const* d_in, const int* in_sizes, int n_in,
                              void* d_out, int out_size, void* d_ws, size_t ws_size,
                              hipStream_t stream) {
  const float* phi = (const float*)d_in[0];
  const float* wMr = (const float*)d_in[1];
  const float* wMi = (const float*)d_in[2];
  const float* vM  = (const float*)d_in[3];
  const float* W1e = (const float*)d_in[4];
  const float* b1e = (const float*)d_in[5];
  const float* W2e = (const float*)d_in[6];
  const float* b2e = (const float*)d_in[7];
  const float* W1r = (const float*)d_in[8];
  const float* b1r = (const float*)d_in[9];
  const float* W2r = (const float*)d_in[10];
  const float* b2r = (const float*)d_in[11];

  float* out0 = (float*)d_out;            // phi_optimal [B, LS]
  float* out1 = out0 + (size_t)B_ * LS_;  // eta_M^T     [B, LS, M]

  bf16* Awr   = (bf16*)d_ws;                         // [4096, 2048]
  bf16* W1sT  = Awr  + (size_t)ROWS * KW;            // [4096, 2048]
  bf16* W1wT  = W1sT + (size_t)N1 * KW;              // [4096, 2048]
  bf16* h     = W1wT + (size_t)N1 * KW;              // [4096, 4096] (eta half used)
  bf16* W2t   = h + (size_t)ROWS * N1;               // [1024, 2048]
  bf16* sfeat = W2t + (size_t)LS_ * H_;              // [256, 2048]
  float* hSp  = (float*)(sfeat + (size_t)B_ * 2048); // 4 x [256, 4096] partials
  float* hS2  = hSp + (size_t)4 * B_ * N1;           // [256, 4096] summed + bias
  float* hVT  = hS2 + (size_t)B_ * N1;               // [4096, 16]
  float* rhoP = hVT + (size_t)N1 * 16;               // [4096, 8] rho partials

  (void)hipFuncSetAttribute(reinterpret_cast<const void*>(gemm1_256_kernel),
                            hipFuncAttributeMaxDynamicSharedMemorySize, 131072);
  (void)hipFuncSetAttribute(reinterpret_cast<const void*>(gemm128_pipe_kernel<0, 64>),
                            hipFuncAttributeMaxDynamicSharedMemorySize, 66048);
  (void)hipFuncSetAttribute(reinterpret_cast<const void*>(gemm128_pipe_kernel<1, 16>),
                            hipFuncAttributeMaxDynamicSharedMemorySize, 65536);

  // merged preprocessing: hv | 4x W1-transpose | W2-transpose | awr | sfeat
  prep_kernel<<<9984, 256, 0, stream>>>(phi, wMr, wMi, vM, W1e, W1r, W2e,
                                        sfeat, Awr, W1sT, W1wT, W2t, hVT);

  // GEMM_S split-K x4: hSp[z] = sfeat @ W1sT[:, z*512:(z+1)*512]^T
  gemm128_pipe_kernel<1, 16><<<dim3(N1 / 128, B_ / 128, 4), 256, 65536, stream>>>(
      sfeat, 2048, W1sT, KW, nullptr, nullptr, nullptr, nullptr, hSp, nullptr);

  // hS2 = sum4(hSp) + bias
  hsum_kernel<<<(B_ * N1 / 4) / 256, 256, 0, stream>>>(hSp, b1e, b1r, hS2);

  // GEMM_W: h(eta half) = relu(Awr@W1wT^T + hS2 + hVT); rho partials for
  // col-blocks >= 8 (rho half of h never stored)
  gemm1_256_kernel<<<dim3(N1 / 256, ROWS / 256), 512, 131072, stream>>>(
      Awr, W1wT, hS2, hVT, W2r, h, rhoP);

  // GEMM2: rho reduce (prologue) + out1 scatter + out0 = phi - eta
  gemm128_pipe_kernel<0, 64><<<dim3(LS_ / 128, ROWS / 128), 256, 66048, stream>>>(
      h, N1, W2t, H_, b2e, rhoP, b2r, phi, out1, out0);
}